// Round 2
// baseline (3211.292 us; speedup 1.0000x reference)
//
#include <hip/hip_runtime.h>
#include <math.h>

#define NROW 8192
#define DDIM 128
#define CAP 65536
#define NITERS 100
#define AC (1.0f / 8192.0f)

struct Entry { int i, j; float s, t; };

// ws layout (bytes):
// 0       : x2  float[NROW]          (32768)
// 32768   : y2  float[NROW]          (32768)
// 65536   : counts int[8]            { [0..2]=list counts, [3..5]=active off-diag counts }
// 65600   : accum double[3][264]     { [0]=Su [1]=Sv [2]=Sux2 [3]=Svy2 [4]=Ssp, [8..135]=P, [136..263]=Q }
// 71936   : lists Entry[3][CAP]      (3 MiB)
// 3217664 : sdiag float[3][NROW]     (98304)
// 3315968 : tdiag float[3][NROW]     (98304)

__global__ void init_k(int* counts, double* accum, float* sdiag, float* tdiag) {
    int idx = blockIdx.x * 256 + threadIdx.x;
    if (idx < 8) counts[idx] = 0;
    if (idx < 3 * 264) accum[idx] = 0.0;
    if (idx < 3 * NROW) { sdiag[idx] = 0.f; tdiag[idx] = 0.f; }
}

__global__ void norms_k(const float* __restrict__ X, const float* __restrict__ Y,
                        float* __restrict__ x2, float* __restrict__ y2) {
    int gw = (blockIdx.x * blockDim.x + threadIdx.x) >> 6;
    int lane = threadIdx.x & 63;
    if (gw >= 2 * NROW) return;
    const float* M = (gw < NROW) ? X : Y;
    float* out = (gw < NROW) ? x2 : y2;
    int r = (gw < NROW) ? gw : gw - NROW;
    float2 v = *(const float2*)(M + (size_t)r * DDIM + lane * 2);
    float s = v.x * v.x + v.y * v.y;
    for (int o = 32; o; o >>= 1) s += __shfl_down(s, o, 64);
    if (lane == 0) out[r] = s;
}

// prune: 8-dim partial distance lower bound; push candidate (i,j) pairs
__global__ __launch_bounds__(256) void prune_k(const float* __restrict__ X,
                                               const float* __restrict__ Y,
                                               int* counts, Entry* lists) {
    int p = blockIdx.y;
    const float* A = (p == 2) ? Y : X;
    const float* B = (p == 0) ? Y : ((p == 1) ? X : Y);
    int i0 = blockIdx.x * 128;
    __shared__ float A9[128][9];
    int t = threadIdx.x;
    {
        int r = t >> 1, c = (t & 1) * 4;
        float4 v = *(const float4*)(A + (size_t)(i0 + r) * DDIM + c);
        A9[r][c + 0] = v.x; A9[r][c + 1] = v.y; A9[r][c + 2] = v.z; A9[r][c + 3] = v.w;
    }
    __syncthreads();
    if (t < 128) {
        float pn = 0.f;
        #pragma unroll
        for (int k = 0; k < 8; k++) pn += A9[t][k] * A9[t][k];
        A9[t][8] = pn;
    }
    __syncthreads();
    Entry* list = lists + (size_t)p * CAP;
    for (int jc = 0; jc < 8; jc++) {
        int jbase = jc * 1024;
        float b[4][8]; float pnb[4];
        #pragma unroll
        for (int k = 0; k < 4; k++) {
            int j = jbase + t + 256 * k;
            float4 v0 = *(const float4*)(B + (size_t)j * DDIM);
            float4 v1 = *(const float4*)(B + (size_t)j * DDIM + 4);
            b[k][0] = v0.x; b[k][1] = v0.y; b[k][2] = v0.z; b[k][3] = v0.w;
            b[k][4] = v1.x; b[k][5] = v1.y; b[k][6] = v1.z; b[k][7] = v1.w;
            float pn = 0.f;
            #pragma unroll
            for (int m = 0; m < 8; m++) pn += b[k][m] * b[k][m];
            pnb[k] = pn;
        }
        for (int r = 0; r < 128; r++) {
            float a[8];
            #pragma unroll
            for (int m = 0; m < 8; m++) a[m] = A9[r][m];
            float pna = A9[r][8];
            #pragma unroll
            for (int k = 0; k < 4; k++) {
                float dot = 0.f;
                #pragma unroll
                for (int m = 0; m < 8; m++) dot = fmaf(a[m], b[k][m], dot);
                float d = fmaf(-2.f, dot, pna + pnb[k]);
                if (d < 0.25f) {
                    int idx = atomicAdd(&counts[p], 1);
                    if (idx < CAP) { list[idx].i = i0 + r; list[idx].j = jbase + t + 256 * k; }
                }
            }
        }
    }
}

// exact: full 128-dim distance for survivors; compute S value and cost correction
__global__ __launch_bounds__(256) void exact_k(const float* __restrict__ X,
                                               const float* __restrict__ Y,
                                               const float* __restrict__ x2,
                                               const float* __restrict__ y2,
                                               const int* counts, Entry* lists) {
    int p = blockIdx.y;
    const float* A = (p == 2) ? Y : X;
    const float* B = (p == 0) ? Y : ((p == 1) ? X : Y);
    const float* na = (p == 2) ? y2 : x2;
    const float* nb = (p == 0) ? y2 : ((p == 1) ? x2 : y2);
    int cnt = counts[p]; if (cnt > CAP) cnt = CAP;
    Entry* list = lists + (size_t)p * CAP;
    int w = (blockIdx.x * 256 + threadIdx.x) >> 6;
    int lane = threadIdx.x & 63;
    for (int e = w; e < cnt; e += 8192) {
        int i = list[e].i, j = list[e].j;
        const float* ar = A + (size_t)i * DDIM;
        const float* br = B + (size_t)j * DDIM;
        float dot = ar[lane] * br[lane] + ar[lane + 64] * br[lane + 64];
        for (int o = 32; o; o >>= 1) dot += __shfl_down(dot, o, 64);
        if (lane == 0) {
            float raw = na[i] + nb[j] - 2.0f * dot;
            float C = fmaxf(raw, 0.0f);
            float sc = fmaxf(-C * 100.0f, -50.0f);
            float K = fmaxf(expf(sc), 1e-8f);
            list[e].s = K - 1e-8f;
            list[e].t = K * C - 1e-8f * raw;
        }
    }
}

// compact: diagonal entries -> dense arrays; count active off-diagonal entries
__global__ void compact_k(const int* counts, const Entry* __restrict__ lists,
                          float* __restrict__ sdiag, float* __restrict__ tdiag,
                          int* rescnt) {
    int p = blockIdx.y;
    int cnt = counts[p]; if (cnt > CAP) cnt = CAP;
    int e = blockIdx.x * 256 + threadIdx.x;
    if (e >= cnt) return;
    Entry en = lists[(size_t)p * CAP + e];
    if (en.i == en.j) {
        sdiag[p * NROW + en.i] = en.s;
        tdiag[p * NROW + en.i] = en.t;
    } else if (en.s != 0.f || en.t != 0.f) {
        atomicAdd(&rescnt[p], 1);
    }
}

// Sinkhorn: fast path (S diagonal -> register-resident, 1 barrier/phase),
// fallback (active off-diagonal entries -> LDS scatter machinery).
__global__ __launch_bounds__(512) void sink2_k(const float* __restrict__ X,
                                               const float* __restrict__ Y,
                                               const float* __restrict__ x2,
                                               const float* __restrict__ y2,
                                               const int* counts, const Entry* __restrict__ lists,
                                               const float* __restrict__ sdiag,
                                               const float* __restrict__ tdiag,
                                               double* accum) {
    int p = blockIdx.x;
    const float* A = (p == 2) ? Y : X;
    const float* B = (p == 0) ? Y : ((p == 1) ? X : Y);
    const float* na = (p == 2) ? y2 : x2;
    const float* nb = (p == 0) ? y2 : ((p == 1) ? x2 : y2);
    const Entry* list = lists + (size_t)p * CAP;
    int cnt = counts[p]; if (cnt > CAP) cnt = CAP;
    int nres = counts[3 + p];
    double* acc = accum + (size_t)p * 264;

    __shared__ float u_s[NROW];
    __shared__ float v_s[NROW];
    __shared__ float red[2][8];
    int t = threadIdx.x;
    int wid = t >> 6, lane = t & 63;
    double sp = 0.0;

    if (nres == 0) {
        // -------- fast path: S is diagonal --------
        float vk[16], uk[16], sk[16];
        #pragma unroll
        for (int k = 0; k < 16; k++) { sk[k] = sdiag[p * NROW + t + 512 * k]; vk[k] = 1.0f; }
        int par = 0;
        for (int it = 0; it < NITERS; it++) {
            // phase A: u = a / max(1e-8*sum(v) + s_i*v_i, 1e-8)
            float s = 0.f;
            #pragma unroll
            for (int k = 0; k < 16; k++) s += vk[k];
            for (int o = 32; o; o >>= 1) s += __shfl_down(s, o, 64);
            if (lane == 0) red[par][wid] = s;
            __syncthreads();
            float sumv = red[par][0] + red[par][1] + red[par][2] + red[par][3]
                       + red[par][4] + red[par][5] + red[par][6] + red[par][7];
            par ^= 1;
            float base = 1e-8f * sumv;
            #pragma unroll
            for (int k = 0; k < 16; k++) {
                float kv = fmaxf(base + sk[k] * vk[k], 1e-8f);
                uk[k] = AC * __builtin_amdgcn_rcpf(kv);
            }
            // phase B: v = b / max(1e-8*sum(u) + s_j*u_j, 1e-8)
            s = 0.f;
            #pragma unroll
            for (int k = 0; k < 16; k++) s += uk[k];
            for (int o = 32; o; o >>= 1) s += __shfl_down(s, o, 64);
            if (lane == 0) red[par][wid] = s;
            __syncthreads();
            float sumu = red[par][0] + red[par][1] + red[par][2] + red[par][3]
                       + red[par][4] + red[par][5] + red[par][6] + red[par][7];
            par ^= 1;
            base = 1e-8f * sumu;
            #pragma unroll
            for (int k = 0; k < 16; k++) {
                float kv = fmaxf(base + sk[k] * uk[k], 1e-8f);
                vk[k] = AC * __builtin_amdgcn_rcpf(kv);
            }
        }
        // publish to LDS for common epilogue; sparse correction from registers
        #pragma unroll
        for (int k = 0; k < 16; k++) {
            int i = t + 512 * k;
            u_s[i] = uk[k]; v_s[i] = vk[k];
            sp += (double)uk[k] * (double)vk[k] * (double)tdiag[p * NROW + i];
        }
    } else {
        // -------- fallback: general sparse scatter --------
        for (int i = t; i < NROW; i += 512) { u_s[i] = 1.0f; v_s[i] = 1.0f; }
        __syncthreads();
        for (int it = 0; it < NITERS; it++) {
            {
                float sv = 0.f;
                for (int i = t; i < NROW; i += 512) sv += v_s[i];
                for (int o = 32; o; o >>= 1) sv += __shfl_down(sv, o, 64);
                if (lane == 0) u_s[wid] = sv;
                __syncthreads();
                if (t < 64) {
                    float s2 = (t < 8) ? u_s[t] : 0.f;
                    for (int o = 4; o; o >>= 1) s2 += __shfl_down(s2, o, 64);
                    if (t == 0) u_s[0] = s2;
                }
                __syncthreads();
                float sum_v = u_s[0];
                __syncthreads();
                for (int i = t; i < NROW; i += 512) u_s[i] = 1e-8f * sum_v;
                __syncthreads();
                for (int e = t; e < cnt; e += 512)
                    atomicAdd(&u_s[list[e].i], list[e].s * v_s[list[e].j]);
                __syncthreads();
                for (int i = t; i < NROW; i += 512) u_s[i] = AC / fmaxf(u_s[i], 1e-8f);
                __syncthreads();
            }
            {
                float su = 0.f;
                for (int i = t; i < NROW; i += 512) su += u_s[i];
                for (int o = 32; o; o >>= 1) su += __shfl_down(su, o, 64);
                if (lane == 0) v_s[wid] = su;
                __syncthreads();
                if (t < 64) {
                    float s2 = (t < 8) ? v_s[t] : 0.f;
                    for (int o = 4; o; o >>= 1) s2 += __shfl_down(s2, o, 64);
                    if (t == 0) v_s[0] = s2;
                }
                __syncthreads();
                float sum_u = v_s[0];
                __syncthreads();
                for (int i = t; i < NROW; i += 512) v_s[i] = 1e-8f * sum_u;
                __syncthreads();
                for (int e = t; e < cnt; e += 512)
                    atomicAdd(&v_s[list[e].j], list[e].s * u_s[list[e].i]);
                __syncthreads();
                for (int i = t; i < NROW; i += 512) v_s[i] = AC / fmaxf(v_s[i], 1e-8f);
                __syncthreads();
            }
        }
        for (int e = t; e < cnt; e += 512)
            sp += (double)u_s[list[e].i] * (double)v_s[list[e].j] * (double)list[e].t;
    }
    __syncthreads();

    // -------- common epilogue --------
    {
        double pSu = 0, pSv = 0, pSux2 = 0, pSvy2 = 0;
        for (int i = t; i < NROW; i += 512) {
            double ui = u_s[i], vi = v_s[i];
            pSu += ui; pSv += vi;
            pSux2 += ui * (double)na[i];
            pSvy2 += vi * (double)nb[i];
        }
        for (int o = 32; o; o >>= 1) {
            pSu += __shfl_down(pSu, o, 64);     pSv += __shfl_down(pSv, o, 64);
            pSux2 += __shfl_down(pSux2, o, 64); pSvy2 += __shfl_down(pSvy2, o, 64);
        }
        if (lane == 0) {
            atomicAdd(&acc[0], pSu); atomicAdd(&acc[1], pSv);
            atomicAdd(&acc[2], pSux2); atomicAdd(&acc[3], pSvy2);
        }
    }
    {
        int dq = (t & 31) * 4, g = t >> 5;  // 16 row-groups, 4 dims/thread
        double pp[4] = {0, 0, 0, 0}, qq[4] = {0, 0, 0, 0};
        for (int i = g; i < NROW; i += 16) {
            float4 av = *(const float4*)(A + (size_t)i * DDIM + dq);
            float us = u_s[i];
            pp[0] += (double)us * av.x; pp[1] += (double)us * av.y;
            pp[2] += (double)us * av.z; pp[3] += (double)us * av.w;
            float4 bv = *(const float4*)(B + (size_t)i * DDIM + dq);
            float vs = v_s[i];
            qq[0] += (double)vs * bv.x; qq[1] += (double)vs * bv.y;
            qq[2] += (double)vs * bv.z; qq[3] += (double)vs * bv.w;
        }
        #pragma unroll
        for (int m = 0; m < 4; m++) {
            atomicAdd(&acc[8 + dq + m], pp[m]);
            atomicAdd(&acc[136 + dq + m], qq[m]);
        }
    }
    {
        for (int o = 32; o; o >>= 1) sp += __shfl_down(sp, o, 64);
        if (lane == 0) atomicAdd(&acc[4], sp);
    }
}

__global__ void combine_k(const double* __restrict__ accum, float* __restrict__ out) {
    int t = threadIdx.x;  // 64 threads
    __shared__ double costs[3];
    for (int p = 0; p < 3; p++) {
        const double* acc = accum + (size_t)p * 264;
        double part = acc[8 + t] * acc[136 + t] + acc[8 + 64 + t] * acc[136 + 64 + t];
        for (int o = 32; o; o >>= 1) part += __shfl_down(part, o, 64);
        if (t == 0) {
            double F = acc[2] * acc[1] + acc[0] * acc[3] - 2.0 * part;
            double c = 1e-8 * F + acc[4];
            costs[p] = (c > 0.0) ? c : 0.0;
        }
    }
    __syncthreads();
    if (t == 0) {
        double dv = costs[0] - 0.5 * (costs[1] + costs[2]);
        dv = fmin(fmax(dv, 0.0), 10000.0);
        out[0] = (float)dv;
    }
}

extern "C" void kernel_launch(void* const* d_in, const int* in_sizes, int n_in,
                              void* d_out, int out_size, void* d_ws, size_t ws_size,
                              hipStream_t stream) {
    const float* X = (const float*)d_in[0];
    const float* Y = (const float*)d_in[1];
    float* out = (float*)d_out;
    char* ws = (char*)d_ws;
    float* x2 = (float*)ws;
    float* y2 = (float*)(ws + 32768);
    int* counts = (int*)(ws + 65536);
    double* accum = (double*)(ws + 65600);
    Entry* lists = (Entry*)(ws + 71936);
    float* sdiag = (float*)(ws + 3217664);
    float* tdiag = (float*)(ws + 3315968);

    init_k<<<(3 * NROW + 255) / 256, 256, 0, stream>>>(counts, accum, sdiag, tdiag);
    norms_k<<<(2 * NROW) / 4, 256, 0, stream>>>(X, Y, x2, y2);
    prune_k<<<dim3(NROW / 128, 3), 256, 0, stream>>>(X, Y, counts, lists);
    exact_k<<<dim3(2048, 3), 256, 0, stream>>>(X, Y, x2, y2, counts, lists);
    compact_k<<<dim3(CAP / 256, 3), 256, 0, stream>>>(counts, lists, sdiag, tdiag, counts + 3);
    sink2_k<<<3, 512, 0, stream>>>(X, Y, x2, y2, counts, lists, sdiag, tdiag, accum);
    combine_k<<<1, 64, 0, stream>>>(accum, out);
}

// Round 3
// 502.537 us; speedup vs baseline: 6.3902x; 6.3902x over previous
//
#include <hip/hip_runtime.h>
#include <math.h>

#define NROW 8192
#define DDIM 128
#define CAP 65536
#define NITERS 100
#define AC (1.0f / 8192.0f)

struct Entry { int i, j; float s, t; };

// ws layout (bytes):
// 0       : x2  float[NROW]          (32768)
// 32768   : y2  float[NROW]          (32768)
// 65536   : counts int[8]            { [0..2]=list counts, [3..5]=active off-diag counts }
// 65600   : accum double[3][264]     { [0]=Su [1]=Sv [2]=Sux2 [3]=Svy2 [4]=Ssp, [8..135]=P, [136..263]=Q }
// 71936   : lists Entry[3][CAP]      (3 MiB)
// 3217664 : sdiag float[3][NROW]     (98304)
// 3315968 : tdiag float[3][NROW]     (98304)

__global__ void init_k(int* counts, double* accum, float* sdiag, float* tdiag) {
    int idx = blockIdx.x * 256 + threadIdx.x;
    if (idx < 8) counts[idx] = 0;
    if (idx < 3 * 264) accum[idx] = 0.0;
    if (idx < 3 * NROW) { sdiag[idx] = 0.f; tdiag[idx] = 0.f; }
}

__global__ void norms_k(const float* __restrict__ X, const float* __restrict__ Y,
                        float* __restrict__ x2, float* __restrict__ y2) {
    int gw = (blockIdx.x * blockDim.x + threadIdx.x) >> 6;
    int lane = threadIdx.x & 63;
    if (gw >= 2 * NROW) return;
    const float* M = (gw < NROW) ? X : Y;
    float* out = (gw < NROW) ? x2 : y2;
    int r = (gw < NROW) ? gw : gw - NROW;
    float2 v = *(const float2*)(M + (size_t)r * DDIM + lane * 2);
    float s = v.x * v.x + v.y * v.y;
    for (int o = 32; o; o >>= 1) s += __shfl_down(s, o, 64);
    if (lane == 0) out[r] = s;
}

// prune: 8-dim partial distance lower bound; push candidate (i,j) pairs.
// grid (64 row-blocks, 8 j-chunks, 3 pairs) for occupancy.
__global__ __launch_bounds__(256) void prune_k(const float* __restrict__ X,
                                               const float* __restrict__ Y,
                                               int* counts, Entry* lists) {
    int p = blockIdx.z;
    const float* A = (p == 2) ? Y : X;
    const float* B = (p == 0) ? Y : ((p == 1) ? X : Y);
    int i0 = blockIdx.x * 128;
    int jbase = blockIdx.y * 1024;
    __shared__ float A9[128][9];
    int t = threadIdx.x;
    {
        int r = t >> 1, c = (t & 1) * 4;
        float4 v = *(const float4*)(A + (size_t)(i0 + r) * DDIM + c);
        A9[r][c + 0] = v.x; A9[r][c + 1] = v.y; A9[r][c + 2] = v.z; A9[r][c + 3] = v.w;
    }
    __syncthreads();
    if (t < 128) {
        float pn = 0.f;
        #pragma unroll
        for (int k = 0; k < 8; k++) pn += A9[t][k] * A9[t][k];
        A9[t][8] = pn;
    }
    __syncthreads();
    Entry* list = lists + (size_t)p * CAP;
    float b[4][8]; float pnb[4];
    #pragma unroll
    for (int k = 0; k < 4; k++) {
        int j = jbase + t + 256 * k;
        float4 v0 = *(const float4*)(B + (size_t)j * DDIM);
        float4 v1 = *(const float4*)(B + (size_t)j * DDIM + 4);
        b[k][0] = v0.x; b[k][1] = v0.y; b[k][2] = v0.z; b[k][3] = v0.w;
        b[k][4] = v1.x; b[k][5] = v1.y; b[k][6] = v1.z; b[k][7] = v1.w;
        float pn = 0.f;
        #pragma unroll
        for (int m = 0; m < 8; m++) pn += b[k][m] * b[k][m];
        pnb[k] = pn;
    }
    for (int r = 0; r < 128; r++) {
        float a[8];
        #pragma unroll
        for (int m = 0; m < 8; m++) a[m] = A9[r][m];
        float pna = A9[r][8];
        #pragma unroll
        for (int k = 0; k < 4; k++) {
            float dot = 0.f;
            #pragma unroll
            for (int m = 0; m < 8; m++) dot = fmaf(a[m], b[k][m], dot);
            float d = fmaf(-2.f, dot, pna + pnb[k]);
            if (d < 0.25f) {
                int idx = atomicAdd(&counts[p], 1);
                if (idx < CAP) { list[idx].i = i0 + r; list[idx].j = jbase + t + 256 * k; }
            }
        }
    }
}

// exact: full 128-dim distance for survivors.
// t computed so it is EXACTLY zero when s==0 (no FMA-contraction residue).
__global__ __launch_bounds__(256) void exact_k(const float* __restrict__ X,
                                               const float* __restrict__ Y,
                                               const float* __restrict__ x2,
                                               const float* __restrict__ y2,
                                               const int* counts, Entry* lists) {
    int p = blockIdx.y;
    const float* A = (p == 2) ? Y : X;
    const float* B = (p == 0) ? Y : ((p == 1) ? X : Y);
    const float* na = (p == 2) ? y2 : x2;
    const float* nb = (p == 0) ? y2 : ((p == 1) ? x2 : y2);
    int cnt = counts[p]; if (cnt > CAP) cnt = CAP;
    Entry* list = lists + (size_t)p * CAP;
    int w = (blockIdx.x * 256 + threadIdx.x) >> 6;
    int lane = threadIdx.x & 63;
    for (int e = w; e < cnt; e += 8192) {
        int i = list[e].i, j = list[e].j;
        const float* ar = A + (size_t)i * DDIM;
        const float* br = B + (size_t)j * DDIM;
        float dot = ar[lane] * br[lane] + ar[lane + 64] * br[lane + 64];
        for (int o = 32; o; o >>= 1) dot += __shfl_down(dot, o, 64);
        if (lane == 0) {
            float raw = na[i] + nb[j] - 2.0f * dot;
            float C = fmaxf(raw, 0.0f);
            float sc = fmaxf(-C * 100.0f, -50.0f);
            float K = fmaxf(expf(sc), 1e-8f);
            float s = K - 1e-8f;
            // K*C - 1e-8*raw, algebraically: raw>=0 -> (K-1e-8)*C; raw<0 -> C=0,K=1 -> -1e-8*raw
            list[e].s = s;
            list[e].t = (raw >= 0.f) ? s * C : (-1e-8f) * raw;
        }
    }
}

// compact: diagonal entries -> dense arrays; count active off-diagonal entries
__global__ void compact_k(const int* counts, const Entry* __restrict__ lists,
                          float* __restrict__ sdiag, float* __restrict__ tdiag,
                          int* rescnt) {
    int p = blockIdx.y;
    int cnt = counts[p]; if (cnt > CAP) cnt = CAP;
    int e = blockIdx.x * 256 + threadIdx.x;
    if (e >= cnt) return;
    Entry en = lists[(size_t)p * CAP + e];
    if (en.i == en.j) {
        sdiag[p * NROW + en.i] = en.s;
        tdiag[p * NROW + en.i] = en.t;
    } else if (en.s != 0.f || en.t != 0.f) {
        atomicAdd(&rescnt[p], 1);
    }
}

// Sinkhorn: fast path (S diagonal -> register-resident, 1 barrier/phase),
// fallback (active off-diagonal entries -> LDS scatter machinery).
__global__ __launch_bounds__(1024, 1) void sink2_k(const float* __restrict__ X,
                                                   const float* __restrict__ Y,
                                                   const float* __restrict__ x2,
                                                   const float* __restrict__ y2,
                                                   const int* counts, const Entry* __restrict__ lists,
                                                   const float* __restrict__ sdiag,
                                                   const float* __restrict__ tdiag,
                                                   double* accum) {
    int p = blockIdx.x;
    const float* A = (p == 2) ? Y : X;
    const float* B = (p == 0) ? Y : ((p == 1) ? X : Y);
    const float* na = (p == 2) ? y2 : x2;
    const float* nb = (p == 0) ? y2 : ((p == 1) ? x2 : y2);
    const Entry* list = lists + (size_t)p * CAP;
    int cnt = counts[p]; if (cnt > CAP) cnt = CAP;
    int nres = counts[3 + p];
    double* acc = accum + (size_t)p * 264;

    __shared__ float u_s[NROW];
    __shared__ float v_s[NROW];
    __shared__ float red[2][16];
    int t = threadIdx.x;
    int wid = t >> 6, lane = t & 63;
    double sp = 0.0;

    if (nres == 0) {
        // -------- fast path: S is diagonal; u,v,s live in registers --------
        float vk[8], uk[8], sk[8];
        #pragma unroll
        for (int k = 0; k < 8; k++) { sk[k] = sdiag[p * NROW + t + 1024 * k]; vk[k] = 1.0f; }
        int par = 0;
        for (int it = 0; it < NITERS; it++) {
            // phase A: u = a / max(1e-8*sum(v) + s_i*v_i, 1e-8)
            float s = 0.f;
            #pragma unroll
            for (int k = 0; k < 8; k++) s += vk[k];
            for (int o = 32; o; o >>= 1) s += __shfl_down(s, o, 64);
            if (lane == 0) red[par][wid] = s;
            __syncthreads();
            float sumv = 0.f;
            #pragma unroll
            for (int w2 = 0; w2 < 16; w2++) sumv += red[par][w2];
            par ^= 1;
            float base = 1e-8f * sumv;
            #pragma unroll
            for (int k = 0; k < 8; k++) {
                float kv = fmaxf(base + sk[k] * vk[k], 1e-8f);
                uk[k] = AC * __builtin_amdgcn_rcpf(kv);
            }
            // phase B: v = b / max(1e-8*sum(u) + s_j*u_j, 1e-8)
            s = 0.f;
            #pragma unroll
            for (int k = 0; k < 8; k++) s += uk[k];
            for (int o = 32; o; o >>= 1) s += __shfl_down(s, o, 64);
            if (lane == 0) red[par][wid] = s;
            __syncthreads();
            float sumu = 0.f;
            #pragma unroll
            for (int w2 = 0; w2 < 16; w2++) sumu += red[par][w2];
            par ^= 1;
            base = 1e-8f * sumu;
            #pragma unroll
            for (int k = 0; k < 8; k++) {
                float kv = fmaxf(base + sk[k] * uk[k], 1e-8f);
                vk[k] = AC * __builtin_amdgcn_rcpf(kv);
            }
        }
        // publish to LDS for common epilogue; sparse correction from registers
        #pragma unroll
        for (int k = 0; k < 8; k++) {
            int i = t + 1024 * k;
            u_s[i] = uk[k]; v_s[i] = vk[k];
            sp += (double)uk[k] * (double)vk[k] * (double)tdiag[p * NROW + i];
        }
    } else {
        // -------- fallback: general sparse scatter --------
        for (int i = t; i < NROW; i += 1024) { u_s[i] = 1.0f; v_s[i] = 1.0f; }
        __syncthreads();
        for (int it = 0; it < NITERS; it++) {
            {
                float sv = 0.f;
                for (int i = t; i < NROW; i += 1024) sv += v_s[i];
                for (int o = 32; o; o >>= 1) sv += __shfl_down(sv, o, 64);
                if (lane == 0) u_s[wid] = sv;
                __syncthreads();
                if (t < 64) {
                    float s2 = (t < 16) ? u_s[t] : 0.f;
                    for (int o = 8; o; o >>= 1) s2 += __shfl_down(s2, o, 64);
                    if (t == 0) u_s[0] = s2;
                }
                __syncthreads();
                float sum_v = u_s[0];
                __syncthreads();
                for (int i = t; i < NROW; i += 1024) u_s[i] = 1e-8f * sum_v;
                __syncthreads();
                for (int e = t; e < cnt; e += 1024)
                    atomicAdd(&u_s[list[e].i], list[e].s * v_s[list[e].j]);
                __syncthreads();
                for (int i = t; i < NROW; i += 1024) u_s[i] = AC / fmaxf(u_s[i], 1e-8f);
                __syncthreads();
            }
            {
                float su = 0.f;
                for (int i = t; i < NROW; i += 1024) su += u_s[i];
                for (int o = 32; o; o >>= 1) su += __shfl_down(su, o, 64);
                if (lane == 0) v_s[wid] = su;
                __syncthreads();
                if (t < 64) {
                    float s2 = (t < 16) ? v_s[t] : 0.f;
                    for (int o = 8; o; o >>= 1) s2 += __shfl_down(s2, o, 64);
                    if (t == 0) v_s[0] = s2;
                }
                __syncthreads();
                float sum_u = v_s[0];
                __syncthreads();
                for (int i = t; i < NROW; i += 1024) v_s[i] = 1e-8f * sum_u;
                __syncthreads();
                for (int e = t; e < cnt; e += 1024)
                    atomicAdd(&v_s[list[e].j], list[e].s * u_s[list[e].i]);
                __syncthreads();
                for (int i = t; i < NROW; i += 1024) v_s[i] = AC / fmaxf(v_s[i], 1e-8f);
                __syncthreads();
            }
        }
        for (int e = t; e < cnt; e += 1024)
            sp += (double)u_s[list[e].i] * (double)v_s[list[e].j] * (double)list[e].t;
    }
    __syncthreads();

    // -------- common epilogue --------
    {
        double pSu = 0, pSv = 0, pSux2 = 0, pSvy2 = 0;
        for (int i = t; i < NROW; i += 1024) {
            double ui = u_s[i], vi = v_s[i];
            pSu += ui; pSv += vi;
            pSux2 += ui * (double)na[i];
            pSvy2 += vi * (double)nb[i];
        }
        for (int o = 32; o; o >>= 1) {
            pSu += __shfl_down(pSu, o, 64);     pSv += __shfl_down(pSv, o, 64);
            pSux2 += __shfl_down(pSux2, o, 64); pSvy2 += __shfl_down(pSvy2, o, 64);
        }
        if (lane == 0) {
            atomicAdd(&acc[0], pSu); atomicAdd(&acc[1], pSv);
            atomicAdd(&acc[2], pSux2); atomicAdd(&acc[3], pSvy2);
        }
    }
    {
        int dq = (t & 31) * 4, g = t >> 5;  // 32 row-groups, 4 dims/thread
        double pp[4] = {0, 0, 0, 0}, qq[4] = {0, 0, 0, 0};
        for (int i = g; i < NROW; i += 32) {
            float4 av = *(const float4*)(A + (size_t)i * DDIM + dq);
            float us = u_s[i];
            pp[0] += (double)us * av.x; pp[1] += (double)us * av.y;
            pp[2] += (double)us * av.z; pp[3] += (double)us * av.w;
            float4 bv = *(const float4*)(B + (size_t)i * DDIM + dq);
            float vs = v_s[i];
            qq[0] += (double)vs * bv.x; qq[1] += (double)vs * bv.y;
            qq[2] += (double)vs * bv.z; qq[3] += (double)vs * bv.w;
        }
        #pragma unroll
        for (int m = 0; m < 4; m++) {
            atomicAdd(&acc[8 + dq + m], pp[m]);
            atomicAdd(&acc[136 + dq + m], qq[m]);
        }
    }
    {
        for (int o = 32; o; o >>= 1) sp += __shfl_down(sp, o, 64);
        if (lane == 0) atomicAdd(&acc[4], sp);
    }
}

__global__ void combine_k(const double* __restrict__ accum, float* __restrict__ out) {
    int t = threadIdx.x;  // 64 threads
    __shared__ double costs[3];
    for (int p = 0; p < 3; p++) {
        const double* acc = accum + (size_t)p * 264;
        double part = acc[8 + t] * acc[136 + t] + acc[8 + 64 + t] * acc[136 + 64 + t];
        for (int o = 32; o; o >>= 1) part += __shfl_down(part, o, 64);
        if (t == 0) {
            double F = acc[2] * acc[1] + acc[0] * acc[3] - 2.0 * part;
            double c = 1e-8 * F + acc[4];
            costs[p] = (c > 0.0) ? c : 0.0;
        }
    }
    __syncthreads();
    if (t == 0) {
        double dv = costs[0] - 0.5 * (costs[1] + costs[2]);
        dv = fmin(fmax(dv, 0.0), 10000.0);
        out[0] = (float)dv;
    }
}

extern "C" void kernel_launch(void* const* d_in, const int* in_sizes, int n_in,
                              void* d_out, int out_size, void* d_ws, size_t ws_size,
                              hipStream_t stream) {
    const float* X = (const float*)d_in[0];
    const float* Y = (const float*)d_in[1];
    float* out = (float*)d_out;
    char* ws = (char*)d_ws;
    float* x2 = (float*)ws;
    float* y2 = (float*)(ws + 32768);
    int* counts = (int*)(ws + 65536);
    double* accum = (double*)(ws + 65600);
    Entry* lists = (Entry*)(ws + 71936);
    float* sdiag = (float*)(ws + 3217664);
    float* tdiag = (float*)(ws + 3315968);

    init_k<<<(3 * NROW + 255) / 256, 256, 0, stream>>>(counts, accum, sdiag, tdiag);
    norms_k<<<(2 * NROW) / 4, 256, 0, stream>>>(X, Y, x2, y2);
    prune_k<<<dim3(NROW / 128, 8, 3), 256, 0, stream>>>(X, Y, counts, lists);
    exact_k<<<dim3(2048, 3), 256, 0, stream>>>(X, Y, x2, y2, counts, lists);
    compact_k<<<dim3(CAP / 256, 3), 256, 0, stream>>>(counts, lists, sdiag, tdiag, counts + 3);
    sink2_k<<<3, 1024, 0, stream>>>(X, Y, x2, y2, counts, lists, sdiag, tdiag, accum);
    combine_k<<<1, 64, 0, stream>>>(accum, out);
}

// Round 4
// 486.330 us; speedup vs baseline: 6.6031x; 1.0333x over previous
//
#include <hip/hip_runtime.h>
#include <math.h>

#define NROW 8192
#define DDIM 128
#define CAP 65536
#define NITERS 100
#define AC (1.0f / 8192.0f)

struct Entry { int i, j; float s, t; };

// ws layout (bytes):
// 0       : x2  float[NROW]          (32768)
// 32768   : y2  float[NROW]          (32768)
// 65536   : counts int[8]            { [0..2]=list counts, [3..5]=active off-diag counts }
// 65600   : accum double[3][264]     { [0]=Su [1]=Sv [2]=Sux2 [3]=Svy2 [4]=Ssp, [8..135]=P, [136..263]=Q }
// 71936   : lists Entry[3][CAP]      (3 MiB)
// 3217664 : sdiag float[3][NROW]     (98304)
// 3315968 : tdiag float[3][NROW]     (98304)
// 3414272 : u_g   float[3][NROW]     (98304)
// 3512576 : v_g   float[3][NROW]     (98304)  -> total 3610880

__global__ void init_k(int* counts, double* accum, float* sdiag, float* tdiag) {
    int idx = blockIdx.x * 256 + threadIdx.x;
    if (idx < 8) counts[idx] = 0;
    if (idx < 3 * 264) accum[idx] = 0.0;
    if (idx < 3 * NROW) { sdiag[idx] = 0.f; tdiag[idx] = 0.f; }
}

__global__ void norms_k(const float* __restrict__ X, const float* __restrict__ Y,
                        float* __restrict__ x2, float* __restrict__ y2) {
    int gw = (blockIdx.x * blockDim.x + threadIdx.x) >> 6;
    int lane = threadIdx.x & 63;
    if (gw >= 2 * NROW) return;
    const float* M = (gw < NROW) ? X : Y;
    float* out = (gw < NROW) ? x2 : y2;
    int r = (gw < NROW) ? gw : gw - NROW;
    float2 v = *(const float2*)(M + (size_t)r * DDIM + lane * 2);
    float s = v.x * v.x + v.y * v.y;
    for (int o = 32; o; o >>= 1) s += __shfl_down(s, o, 64);
    if (lane == 0) out[r] = s;
}

// prune: 8-dim partial distance lower bound; push candidate (i,j) pairs.
// A-tile stored as aligned [128][8] so row reads are 2x ds_read_b128.
__global__ __launch_bounds__(256) void prune_k(const float* __restrict__ X,
                                               const float* __restrict__ Y,
                                               int* counts, Entry* lists) {
    int p = blockIdx.z;
    const float* A = (p == 2) ? Y : X;
    const float* B = (p == 0) ? Y : ((p == 1) ? X : Y);
    int i0 = blockIdx.x * 128;
    int jbase = blockIdx.y * 1024;
    __shared__ float A8[128][8];
    __shared__ float An[128];
    int t = threadIdx.x;
    {
        int r = t >> 1, c = (t & 1) * 4;
        float4 v = *(const float4*)(A + (size_t)(i0 + r) * DDIM + c);
        *(float4*)&A8[r][c] = v;
    }
    __syncthreads();
    if (t < 128) {
        float pn = 0.f;
        #pragma unroll
        for (int k = 0; k < 8; k++) pn += A8[t][k] * A8[t][k];
        An[t] = pn;
    }
    __syncthreads();
    Entry* list = lists + (size_t)p * CAP;
    float b[4][8]; float pnb[4];
    #pragma unroll
    for (int k = 0; k < 4; k++) {
        int j = jbase + t + 256 * k;
        float4 v0 = *(const float4*)(B + (size_t)j * DDIM);
        float4 v1 = *(const float4*)(B + (size_t)j * DDIM + 4);
        b[k][0] = v0.x; b[k][1] = v0.y; b[k][2] = v0.z; b[k][3] = v0.w;
        b[k][4] = v1.x; b[k][5] = v1.y; b[k][6] = v1.z; b[k][7] = v1.w;
        float pn = 0.f;
        #pragma unroll
        for (int m = 0; m < 8; m++) pn += b[k][m] * b[k][m];
        pnb[k] = pn;
    }
    for (int r = 0; r < 128; r++) {
        float4 a0 = *(const float4*)&A8[r][0];
        float4 a1 = *(const float4*)&A8[r][4];
        float pna = An[r];
        float a[8] = {a0.x, a0.y, a0.z, a0.w, a1.x, a1.y, a1.z, a1.w};
        #pragma unroll
        for (int k = 0; k < 4; k++) {
            float dot = 0.f;
            #pragma unroll
            for (int m = 0; m < 8; m++) dot = fmaf(a[m], b[k][m], dot);
            float d = fmaf(-2.f, dot, pna + pnb[k]);
            if (d < 0.25f) {
                int idx = atomicAdd(&counts[p], 1);
                if (idx < CAP) { list[idx].i = i0 + r; list[idx].j = jbase + t + 256 * k; }
            }
        }
    }
}

// exact: full 128-dim distance for survivors.
// t computed so it is EXACTLY zero when s==0 (no FMA-contraction residue).
__global__ __launch_bounds__(256) void exact_k(const float* __restrict__ X,
                                               const float* __restrict__ Y,
                                               const float* __restrict__ x2,
                                               const float* __restrict__ y2,
                                               const int* counts, Entry* lists) {
    int p = blockIdx.y;
    const float* A = (p == 2) ? Y : X;
    const float* B = (p == 0) ? Y : ((p == 1) ? X : Y);
    const float* na = (p == 2) ? y2 : x2;
    const float* nb = (p == 0) ? y2 : ((p == 1) ? x2 : y2);
    int cnt = counts[p]; if (cnt > CAP) cnt = CAP;
    Entry* list = lists + (size_t)p * CAP;
    int w = (blockIdx.x * 256 + threadIdx.x) >> 6;
    int lane = threadIdx.x & 63;
    for (int e = w; e < cnt; e += 8192) {
        int i = list[e].i, j = list[e].j;
        const float* ar = A + (size_t)i * DDIM;
        const float* br = B + (size_t)j * DDIM;
        float dot = ar[lane] * br[lane] + ar[lane + 64] * br[lane + 64];
        for (int o = 32; o; o >>= 1) dot += __shfl_down(dot, o, 64);
        if (lane == 0) {
            float raw = na[i] + nb[j] - 2.0f * dot;
            float C = fmaxf(raw, 0.0f);
            float sc = fmaxf(-C * 100.0f, -50.0f);
            float K = fmaxf(expf(sc), 1e-8f);
            float s = K - 1e-8f;
            list[e].s = s;
            list[e].t = (raw >= 0.f) ? s * C : (-1e-8f) * raw;
        }
    }
}

// compact: diagonal entries -> dense arrays; count active off-diagonal entries
__global__ void compact_k(const int* counts, const Entry* __restrict__ lists,
                          float* __restrict__ sdiag, float* __restrict__ tdiag,
                          int* rescnt) {
    int p = blockIdx.y;
    int cnt = counts[p]; if (cnt > CAP) cnt = CAP;
    int e = blockIdx.x * 256 + threadIdx.x;
    if (e >= cnt) return;
    Entry en = lists[(size_t)p * CAP + e];
    if (en.i == en.j) {
        sdiag[p * NROW + en.i] = en.s;
        tdiag[p * NROW + en.i] = en.t;
    } else if (en.s != 0.f || en.t != 0.f) {
        atomicAdd(&rescnt[p], 1);
    }
}

// Sinkhorn iterations. Fast path: register-resident, early-exit when v reaches
// a bitwise fixed point (iterations are then exact no-ops -> result identical).
// Writes final u,v to global; wide-grid epi_k does the heavy epilogue.
__global__ __launch_bounds__(1024, 1) void sink2_k(const int* counts,
                                                   const Entry* __restrict__ lists,
                                                   const float* __restrict__ sdiag,
                                                   const float* __restrict__ tdiag,
                                                   float* __restrict__ u_g,
                                                   float* __restrict__ v_g,
                                                   double* accum) {
    int p = blockIdx.x;
    const Entry* list = lists + (size_t)p * CAP;
    int cnt = counts[p]; if (cnt > CAP) cnt = CAP;
    int nres = counts[3 + p];
    double* acc = accum + (size_t)p * 264;
    float* up = u_g + (size_t)p * NROW;
    float* vp = v_g + (size_t)p * NROW;

    __shared__ float u_s[NROW];   // fallback only
    __shared__ float v_s[NROW];
    __shared__ float redS[2][16];
    __shared__ unsigned redC[16];
    int t = threadIdx.x;
    int wid = t >> 6, lane = t & 63;
    double sp = 0.0;

    if (nres == 0) {
        // -------- fast path: S diagonal; u,v,s in registers; 2 barriers/iter --------
        float vk[8], uk[8], sk[8];
        #pragma unroll
        for (int k = 0; k < 8; k++) { sk[k] = sdiag[p * NROW + t + 1024 * k]; vk[k] = 1.0f; uk[k] = AC; }
        unsigned chg = 1u;
        int par = 0;
        for (int it = 0; it < NITERS; it++) {
            // phase A: u = a / max(1e-8*sum(v) + s_i*v_i, 1e-8)
            float s = 0.f;
            #pragma unroll
            for (int k = 0; k < 8; k++) s += vk[k];
            for (int o = 32; o; o >>= 1) s += __shfl_down(s, o, 64);
            if (lane == 0) { redS[par][wid] = s; redC[wid] = chg; }
            __syncthreads();
            float sumv = 0.f; unsigned anyc = 0;
            #pragma unroll
            for (int w2 = 0; w2 < 16; w2++) { sumv += redS[par][w2]; anyc |= redC[w2]; }
            par ^= 1;
            if (it > 0 && anyc == 0) break;   // v bitwise-stable -> all further iters identical
            float base = 1e-8f * sumv;
            #pragma unroll
            for (int k = 0; k < 8; k++) {
                float kv = fmaxf(base + sk[k] * vk[k], 1e-8f);
                uk[k] = AC * __builtin_amdgcn_rcpf(kv);
            }
            // phase B: v = b / max(1e-8*sum(u) + s_j*u_j, 1e-8)
            s = 0.f;
            #pragma unroll
            for (int k = 0; k < 8; k++) s += uk[k];
            for (int o = 32; o; o >>= 1) s += __shfl_down(s, o, 64);
            if (lane == 0) redS[par][wid] = s;
            __syncthreads();
            float sumu = 0.f;
            #pragma unroll
            for (int w2 = 0; w2 < 16; w2++) sumu += redS[par][w2];
            par ^= 1;
            base = 1e-8f * sumu;
            unsigned diff = 0;
            #pragma unroll
            for (int k = 0; k < 8; k++) {
                float kv = fmaxf(base + sk[k] * uk[k], 1e-8f);
                float nv = AC * __builtin_amdgcn_rcpf(kv);
                diff |= __float_as_uint(nv) ^ __float_as_uint(vk[k]);
                vk[k] = nv;
            }
            chg = __any(diff != 0) ? 1u : 0u;
        }
        #pragma unroll
        for (int k = 0; k < 8; k++) {
            int i = t + 1024 * k;
            up[i] = uk[k]; vp[i] = vk[k];
            sp += (double)uk[k] * (double)vk[k] * (double)tdiag[p * NROW + i];
        }
    } else {
        // -------- fallback: general sparse scatter --------
        for (int i = t; i < NROW; i += 1024) { u_s[i] = 1.0f; v_s[i] = 1.0f; }
        __syncthreads();
        for (int it = 0; it < NITERS; it++) {
            {
                float sv = 0.f;
                for (int i = t; i < NROW; i += 1024) sv += v_s[i];
                for (int o = 32; o; o >>= 1) sv += __shfl_down(sv, o, 64);
                if (lane == 0) u_s[wid] = sv;
                __syncthreads();
                if (t < 64) {
                    float s2 = (t < 16) ? u_s[t] : 0.f;
                    for (int o = 8; o; o >>= 1) s2 += __shfl_down(s2, o, 64);
                    if (t == 0) u_s[0] = s2;
                }
                __syncthreads();
                float sum_v = u_s[0];
                __syncthreads();
                for (int i = t; i < NROW; i += 1024) u_s[i] = 1e-8f * sum_v;
                __syncthreads();
                for (int e = t; e < cnt; e += 1024)
                    atomicAdd(&u_s[list[e].i], list[e].s * v_s[list[e].j]);
                __syncthreads();
                for (int i = t; i < NROW; i += 1024) u_s[i] = AC / fmaxf(u_s[i], 1e-8f);
                __syncthreads();
            }
            {
                float su = 0.f;
                for (int i = t; i < NROW; i += 1024) su += u_s[i];
                for (int o = 32; o; o >>= 1) su += __shfl_down(su, o, 64);
                if (lane == 0) v_s[wid] = su;
                __syncthreads();
                if (t < 64) {
                    float s2 = (t < 16) ? v_s[t] : 0.f;
                    for (int o = 8; o; o >>= 1) s2 += __shfl_down(s2, o, 64);
                    if (t == 0) v_s[0] = s2;
                }
                __syncthreads();
                float sum_u = v_s[0];
                __syncthreads();
                for (int i = t; i < NROW; i += 1024) v_s[i] = 1e-8f * sum_u;
                __syncthreads();
                for (int e = t; e < cnt; e += 1024)
                    atomicAdd(&v_s[list[e].j], list[e].s * u_s[list[e].i]);
                __syncthreads();
                for (int i = t; i < NROW; i += 1024) v_s[i] = AC / fmaxf(v_s[i], 1e-8f);
                __syncthreads();
            }
        }
        for (int i = t; i < NROW; i += 1024) { up[i] = u_s[i]; vp[i] = v_s[i]; }
        for (int e = t; e < cnt; e += 1024)
            sp += (double)u_s[list[e].i] * (double)v_s[list[e].j] * (double)list[e].t;
    }
    for (int o = 32; o; o >>= 1) sp += __shfl_down(sp, o, 64);
    if (lane == 0) atomicAdd(&acc[4], sp);
}

// wide-grid epilogue: Su, Sv, Sux2, Svy2, P[d]=sum u_i A[i,d], Q[d]=sum v_j B[j,d]
__global__ __launch_bounds__(256) void epi_k(const float* __restrict__ X,
                                             const float* __restrict__ Y,
                                             const float* __restrict__ x2,
                                             const float* __restrict__ y2,
                                             const float* __restrict__ u_g,
                                             const float* __restrict__ v_g,
                                             double* accum) {
    int p = blockIdx.y;
    const float* A = (p == 2) ? Y : X;
    const float* B = (p == 0) ? Y : ((p == 1) ? X : Y);
    const float* na = (p == 2) ? y2 : x2;
    const float* nb = (p == 0) ? y2 : ((p == 1) ? x2 : y2);
    const float* up = u_g + (size_t)p * NROW;
    const float* vp = v_g + (size_t)p * NROW;
    double* acc = accum + (size_t)p * 264;
    int t = threadIdx.x, lane = t & 63;
    int rbase = blockIdx.x * 256;
    {
        int r = rbase + t;
        double ui = up[r], vi = vp[r];
        double a0 = ui, a1 = vi, a2 = ui * (double)na[r], a3 = vi * (double)nb[r];
        for (int o = 32; o; o >>= 1) {
            a0 += __shfl_down(a0, o, 64); a1 += __shfl_down(a1, o, 64);
            a2 += __shfl_down(a2, o, 64); a3 += __shfl_down(a3, o, 64);
        }
        if (lane == 0) {
            atomicAdd(&acc[0], a0); atomicAdd(&acc[1], a1);
            atomicAdd(&acc[2], a2); atomicAdd(&acc[3], a3);
        }
    }
    {
        int dq = (t & 31) * 4, g = t >> 5;  // 8 row-groups x 32 dim-quads
        double pp[4] = {0, 0, 0, 0}, qq[4] = {0, 0, 0, 0};
        for (int k = 0; k < 32; k++) {
            int r = rbase + g + 8 * k;
            float4 av = *(const float4*)(A + (size_t)r * DDIM + dq);
            float us = up[r];
            pp[0] += (double)us * av.x; pp[1] += (double)us * av.y;
            pp[2] += (double)us * av.z; pp[3] += (double)us * av.w;
            float4 bv = *(const float4*)(B + (size_t)r * DDIM + dq);
            float vs = vp[r];
            qq[0] += (double)vs * bv.x; qq[1] += (double)vs * bv.y;
            qq[2] += (double)vs * bv.z; qq[3] += (double)vs * bv.w;
        }
        #pragma unroll
        for (int m = 0; m < 4; m++) {
            atomicAdd(&acc[8 + dq + m], pp[m]);
            atomicAdd(&acc[136 + dq + m], qq[m]);
        }
    }
}

__global__ void combine_k(const double* __restrict__ accum, float* __restrict__ out) {
    int t = threadIdx.x;  // 64 threads
    __shared__ double costs[3];
    for (int p = 0; p < 3; p++) {
        const double* acc = accum + (size_t)p * 264;
        double part = acc[8 + t] * acc[136 + t] + acc[8 + 64 + t] * acc[136 + 64 + t];
        for (int o = 32; o; o >>= 1) part += __shfl_down(part, o, 64);
        if (t == 0) {
            double F = acc[2] * acc[1] + acc[0] * acc[3] - 2.0 * part;
            double c = 1e-8 * F + acc[4];
            costs[p] = (c > 0.0) ? c : 0.0;
        }
    }
    __syncthreads();
    if (t == 0) {
        double dv = costs[0] - 0.5 * (costs[1] + costs[2]);
        dv = fmin(fmax(dv, 0.0), 10000.0);
        out[0] = (float)dv;
    }
}

extern "C" void kernel_launch(void* const* d_in, const int* in_sizes, int n_in,
                              void* d_out, int out_size, void* d_ws, size_t ws_size,
                              hipStream_t stream) {
    const float* X = (const float*)d_in[0];
    const float* Y = (const float*)d_in[1];
    float* out = (float*)d_out;
    char* ws = (char*)d_ws;
    float* x2 = (float*)ws;
    float* y2 = (float*)(ws + 32768);
    int* counts = (int*)(ws + 65536);
    double* accum = (double*)(ws + 65600);
    Entry* lists = (Entry*)(ws + 71936);
    float* sdiag = (float*)(ws + 3217664);
    float* tdiag = (float*)(ws + 3315968);
    float* u_g = (float*)(ws + 3414272);
    float* v_g = (float*)(ws + 3512576);

    init_k<<<(3 * NROW + 255) / 256, 256, 0, stream>>>(counts, accum, sdiag, tdiag);
    norms_k<<<(2 * NROW) / 4, 256, 0, stream>>>(X, Y, x2, y2);
    prune_k<<<dim3(NROW / 128, 8, 3), 256, 0, stream>>>(X, Y, counts, lists);
    exact_k<<<dim3(2048, 3), 256, 0, stream>>>(X, Y, x2, y2, counts, lists);
    compact_k<<<dim3(CAP / 256, 3), 256, 0, stream>>>(counts, lists, sdiag, tdiag, counts + 3);
    sink2_k<<<3, 1024, 0, stream>>>(counts, lists, sdiag, tdiag, u_g, v_g, accum);
    epi_k<<<dim3(NROW / 256, 3), 256, 0, stream>>>(X, Y, x2, y2, u_g, v_g, accum);
    combine_k<<<1, 64, 0, stream>>>(accum, out);
}

// Round 5
// 400.228 us; speedup vs baseline: 8.0236x; 1.2151x over previous
//
#include <hip/hip_runtime.h>
#include <math.h>

#define NROW 8192
#define DDIM 128
#define CAP 16384
#define NITERS 100
#define AC (1.0f / 8192.0f)
#define LSTRIDE 136   // LDS row stride in bf16 elems (272B: 16B-aligned, banks at 8/bank floor)

struct Entry { int i, j; float s, t; };

// ws layout (bytes):
// 0       : x2  float[NROW]              (32768)
// 32768   : y2  float[NROW]              (32768)
// 65536   : counts int[8]                { [0..2]=list counts (pre-seeded 8192 diag), [3..5]=off-diag active }
// 65600   : accum double[3][264]
// 71936   : lists Entry[3][CAP]          (786432) -> ends 858368
// 858368  : Xbf ushort[NROW*DDIM]        (2 MiB)   [OVERLAY: sdiag/tdiag/u_g/v_g live here
//             sdiag @858368  tdiag @956672  u_g @1054976  v_g @1153280 -- written only
//             after scan_k is done reading Xbf]
// 2955520 : Ybf ushort[NROW*DDIM]        (2 MiB) -> total 5052672

typedef __attribute__((ext_vector_type(8))) short frag_ab;   // 8 bf16
typedef __attribute__((ext_vector_type(4))) float frag_cd;   // 4 fp32

__device__ inline unsigned short f2bf(float f) {
    unsigned u = __float_as_uint(f);
    return (unsigned short)((u + 0x7FFFu + ((u >> 16) & 1u)) >> 16);  // RN-even
}

__global__ void init_k(int* counts, double* accum, Entry* lists) {
    int idx = blockIdx.x * 256 + threadIdx.x;
    if (idx < 3) counts[idx] = NROW;          // diagonal pre-seeded below
    else if (idx < 8) counts[idx] = 0;
    if (idx < 3 * 264) accum[idx] = 0.0;
    if (idx < 3 * NROW) {
        int p = idx >> 13, i = idx & (NROW - 1);
        Entry e; e.i = i; e.j = i; e.s = 0.f; e.t = 0.f;
        lists[(size_t)p * CAP + i] = e;
    }
}

// norms + fp32->bf16 conversion
__global__ void norms_k(const float* __restrict__ X, const float* __restrict__ Y,
                        float* __restrict__ x2, float* __restrict__ y2,
                        unsigned short* __restrict__ Xbf, unsigned short* __restrict__ Ybf) {
    int gw = (blockIdx.x * blockDim.x + threadIdx.x) >> 6;
    int lane = threadIdx.x & 63;
    if (gw >= 2 * NROW) return;
    const float* M = (gw < NROW) ? X : Y;
    float* out = (gw < NROW) ? x2 : y2;
    unsigned short* Mb = (gw < NROW) ? Xbf : Ybf;
    int r = (gw < NROW) ? gw : gw - NROW;
    float2 v = *(const float2*)(M + (size_t)r * DDIM + lane * 2);
    unsigned pk = (unsigned)f2bf(v.x) | ((unsigned)f2bf(v.y) << 16);
    *(unsigned*)(Mb + (size_t)r * DDIM + lane * 2) = pk;
    float s = v.x * v.x + v.y * v.y;
    for (int o = 32; o; o >>= 1) s += __shfl_down(s, o, 64);
    if (lane == 0) out[r] = s;
}

// MFMA scan: C~ = x2[i]+y2[j]-2*(Xbf[i].Ybf[j]); push off-diag candidates C~<2.
// Diagonal is pre-seeded by init_k, so this only needs to catch near-duplicates.
__global__ __launch_bounds__(256) void scan_k(const unsigned short* __restrict__ Xbf,
                                              const unsigned short* __restrict__ Ybf,
                                              const float* __restrict__ x2,
                                              const float* __restrict__ y2,
                                              int* counts, Entry* lists) {
    int p = blockIdx.z;
    if (p && blockIdx.y < blockIdx.x) return;   // symmetric pairs: upper triangle only
    const unsigned short* Ab = (p == 2) ? Ybf : Xbf;
    const unsigned short* Bb = (p == 0) ? Ybf : ((p == 1) ? Xbf : Ybf);
    const float* na = (p == 2) ? y2 : x2;
    const float* nb = (p == 0) ? y2 : ((p == 1) ? x2 : y2);
    int i0 = blockIdx.x * 128, j0 = blockIdx.y * 128;

    __shared__ unsigned short As[128 * LSTRIDE];
    __shared__ unsigned short Bs[128 * LSTRIDE];
    int t = threadIdx.x;

    // stage both 128x128 bf16 tiles (each tile contiguous 32KB in global)
    const unsigned short* ga = Ab + (size_t)i0 * DDIM;
    const unsigned short* gb = Bb + (size_t)j0 * DDIM;
    #pragma unroll
    for (int c = 0; c < 8; c++) {
        int u = c * 256 + t;                 // 16B unit
        int row = u >> 4, col = (u & 15) * 8;
        uint4 wa = *(const uint4*)(ga + u * 8);
        uint4 wb = *(const uint4*)(gb + u * 8);
        *(uint4*)&As[row * LSTRIDE + col] = wa;
        *(uint4*)&Bs[row * LSTRIDE + col] = wb;
    }
    __syncthreads();

    int w = t >> 6, lane = t & 63;
    int lm = lane & 15, quad = lane >> 4;
    int wr = (w & 1) * 64, wc = (w >> 1) * 64;

    frag_cd acc[4][4];
    #pragma unroll
    for (int rt = 0; rt < 4; rt++)
        #pragma unroll
        for (int ct = 0; ct < 4; ct++) acc[rt][ct] = (frag_cd){0.f, 0.f, 0.f, 0.f};

    int abase = (wr + lm) * LSTRIDE + quad * 8;
    int bbase = (wc + lm) * LSTRIDE + quad * 8;
    #pragma unroll
    for (int ks = 0; ks < 4; ks++) {
        int k0 = ks * 32;
        frag_ab a[4], b[4];
        #pragma unroll
        for (int rt = 0; rt < 4; rt++) a[rt] = *(const frag_ab*)&As[abase + rt * 16 * LSTRIDE + k0];
        #pragma unroll
        for (int ct = 0; ct < 4; ct++) b[ct] = *(const frag_ab*)&Bs[bbase + ct * 16 * LSTRIDE + k0];
        #pragma unroll
        for (int rt = 0; rt < 4; rt++)
            #pragma unroll
            for (int ct = 0; ct < 4; ct++)
                acc[rt][ct] = __builtin_amdgcn_mfma_f32_16x16x32_bf16(a[rt], b[ct], acc[rt][ct], 0, 0, 0);
    }

    // epilogue: C/D layout col=lane&15, row=quad*4+reg (m89-verified)
    Entry* list = lists + (size_t)p * CAP;
    #pragma unroll
    for (int rt = 0; rt < 4; rt++) {
        #pragma unroll
        for (int ct = 0; ct < 4; ct++) {
            int j = j0 + wc + ct * 16 + lm;
            float yj = nb[j];
            #pragma unroll
            for (int reg = 0; reg < 4; reg++) {
                int i = i0 + wr + rt * 16 + quad * 4 + reg;
                float Ct = na[i] + yj - 2.f * acc[rt][ct][reg];
                if (Ct < 2.0f && i != j) {
                    if (p == 0) {
                        int idx = atomicAdd(&counts[0], 1);
                        if (idx < CAP) { Entry e; e.i = i; e.j = j; e.s = 0.f; e.t = 0.f; list[idx] = e; }
                    } else if (i < j) {
                        int idx = atomicAdd(&counts[p], 2);
                        if (idx < CAP) { Entry e; e.i = i; e.j = j; e.s = 0.f; e.t = 0.f; list[idx] = e; }
                        if (idx + 1 < CAP) { Entry e; e.i = j; e.j = i; e.s = 0.f; e.t = 0.f; list[idx + 1] = e; }
                    }
                }
            }
        }
    }
}

// exact: full 128-dim fp32 distance for every listed entry.
// t computed so it is EXACTLY zero when s==0 (no FMA-contraction residue).
__global__ __launch_bounds__(256) void exact_k(const float* __restrict__ X,
                                               const float* __restrict__ Y,
                                               const float* __restrict__ x2,
                                               const float* __restrict__ y2,
                                               const int* counts, Entry* lists) {
    int p = blockIdx.y;
    const float* A = (p == 2) ? Y : X;
    const float* B = (p == 0) ? Y : ((p == 1) ? X : Y);
    const float* na = (p == 2) ? y2 : x2;
    const float* nb = (p == 0) ? y2 : ((p == 1) ? x2 : y2);
    int cnt = counts[p]; if (cnt > CAP) cnt = CAP;
    Entry* list = lists + (size_t)p * CAP;
    int w = (blockIdx.x * 256 + threadIdx.x) >> 6;
    int lane = threadIdx.x & 63;
    for (int e = w; e < cnt; e += 8192) {
        int i = list[e].i, j = list[e].j;
        const float* ar = A + (size_t)i * DDIM;
        const float* br = B + (size_t)j * DDIM;
        float dot = ar[lane] * br[lane] + ar[lane + 64] * br[lane + 64];
        for (int o = 32; o; o >>= 1) dot += __shfl_down(dot, o, 64);
        if (lane == 0) {
            float raw = na[i] + nb[j] - 2.0f * dot;
            float C = fmaxf(raw, 0.0f);
            float sc = fmaxf(-C * 100.0f, -50.0f);
            float K = fmaxf(expf(sc), 1e-8f);
            float s = K - 1e-8f;
            list[e].s = s;
            list[e].t = (raw >= 0.f) ? s * C : (-1e-8f) * raw;
        }
    }
}

// compact: diagonal entries -> dense arrays; count active off-diagonal entries
__global__ void compact_k(const int* counts, const Entry* __restrict__ lists,
                          float* __restrict__ sdiag, float* __restrict__ tdiag,
                          int* rescnt) {
    int p = blockIdx.y;
    int cnt = counts[p]; if (cnt > CAP) cnt = CAP;
    int e = blockIdx.x * 256 + threadIdx.x;
    if (e >= cnt) return;
    Entry en = lists[(size_t)p * CAP + e];
    if (en.i == en.j) {
        sdiag[p * NROW + en.i] = en.s;
        tdiag[p * NROW + en.i] = en.t;
    } else if (en.s != 0.f || en.t != 0.f) {
        atomicAdd(&rescnt[p], 1);
    }
}

// Sinkhorn. Fast path: register-resident, bit-exact early exit on period-1 AND
// period-2 ulp orbits (parity-corrected). Fallback: general sparse scatter.
__global__ __launch_bounds__(1024, 1) void sink2_k(const int* counts,
                                                   const Entry* __restrict__ lists,
                                                   const float* __restrict__ sdiag,
                                                   const float* __restrict__ tdiag,
                                                   float* __restrict__ u_g,
                                                   float* __restrict__ v_g,
                                                   double* accum) {
    int p = blockIdx.x;
    const Entry* list = lists + (size_t)p * CAP;
    int cnt = counts[p]; if (cnt > CAP) cnt = CAP;
    int nres = counts[3 + p];
    double* acc = accum + (size_t)p * 264;
    float* up = u_g + (size_t)p * NROW;
    float* vp = v_g + (size_t)p * NROW;

    __shared__ float u_s[NROW];   // fallback only
    __shared__ float v_s[NROW];
    __shared__ float redS[2][16];
    __shared__ unsigned redC[16];
    int t = threadIdx.x;
    int wid = t >> 6, lane = t & 63;
    double sp = 0.0;

    if (nres == 0) {
        float vk[8], uk[8], sk[8];
        unsigned pv2[8];   // bits of v_{n-2}
        #pragma unroll
        for (int k = 0; k < 8; k++) {
            sk[k] = sdiag[p * NROW + t + 1024 * k];
            vk[k] = 1.0f; uk[k] = AC; pv2[k] = 0xFFFFFFFFu;
        }
        unsigned flags = 3u;   // bit0: v != v_prev somewhere; bit1: v != v_prevprev somewhere
        int par = 0, last = 0;
        for (int it = 0; it < NITERS; it++) {
            // phase A reduce: sum(v) + convergence flags
            float s = 0.f;
            #pragma unroll
            for (int k = 0; k < 8; k++) s += vk[k];
            for (int o = 32; o; o >>= 1) s += __shfl_down(s, o, 64);
            if (lane == 0) { redS[par][wid] = s; redC[wid] = flags; }
            __syncthreads();
            float sumv = 0.f; unsigned anyf = 0;
            #pragma unroll
            for (int w2 = 0; w2 < 16; w2++) { sumv += redS[par][w2]; anyf |= redC[w2]; }
            par ^= 1;
            if (it > 0) {
                if (!(anyf & 1)) break;               // fixed point: state frozen
                if (!(anyf & 2)) {                    // period-2 orbit
                    if (((NITERS - it) & 1) == 0) break;  // current state == state at iter 99
                    last = 1;                             // need exactly one more iteration
                }
            }
            float base = 1e-8f * sumv;
            #pragma unroll
            for (int k = 0; k < 8; k++) {
                float kv = fmaxf(base + sk[k] * vk[k], 1e-8f);
                uk[k] = AC * __builtin_amdgcn_rcpf(kv);
            }
            // phase B: sum(u), update v
            s = 0.f;
            #pragma unroll
            for (int k = 0; k < 8; k++) s += uk[k];
            for (int o = 32; o; o >>= 1) s += __shfl_down(s, o, 64);
            if (lane == 0) redS[par][wid] = s;
            __syncthreads();
            float sumu = 0.f;
            #pragma unroll
            for (int w2 = 0; w2 < 16; w2++) sumu += redS[par][w2];
            par ^= 1;
            base = 1e-8f * sumu;
            unsigned d1 = 0, d2 = 0;
            #pragma unroll
            for (int k = 0; k < 8; k++) {
                float kv = fmaxf(base + sk[k] * uk[k], 1e-8f);
                float nv = AC * __builtin_amdgcn_rcpf(kv);
                unsigned nb_ = __float_as_uint(nv);
                d1 |= nb_ ^ __float_as_uint(vk[k]);
                d2 |= nb_ ^ pv2[k];
                pv2[k] = __float_as_uint(vk[k]);
                vk[k] = nv;
            }
            flags = (__any(d1 != 0) ? 1u : 0u) | (__any(d2 != 0) ? 2u : 0u);
            if (last) break;
        }
        #pragma unroll
        for (int k = 0; k < 8; k++) {
            int i = t + 1024 * k;
            up[i] = uk[k]; vp[i] = vk[k];
            sp += (double)uk[k] * (double)vk[k] * (double)tdiag[p * NROW + i];
        }
    } else {
        for (int i = t; i < NROW; i += 1024) { u_s[i] = 1.0f; v_s[i] = 1.0f; }
        __syncthreads();
        for (int it = 0; it < NITERS; it++) {
            {
                float sv = 0.f;
                for (int i = t; i < NROW; i += 1024) sv += v_s[i];
                for (int o = 32; o; o >>= 1) sv += __shfl_down(sv, o, 64);
                if (lane == 0) u_s[wid] = sv;
                __syncthreads();
                if (t < 64) {
                    float s2 = (t < 16) ? u_s[t] : 0.f;
                    for (int o = 8; o; o >>= 1) s2 += __shfl_down(s2, o, 64);
                    if (t == 0) u_s[0] = s2;
                }
                __syncthreads();
                float sum_v = u_s[0];
                __syncthreads();
                for (int i = t; i < NROW; i += 1024) u_s[i] = 1e-8f * sum_v;
                __syncthreads();
                for (int e = t; e < cnt; e += 1024)
                    atomicAdd(&u_s[list[e].i], list[e].s * v_s[list[e].j]);
                __syncthreads();
                for (int i = t; i < NROW; i += 1024) u_s[i] = AC / fmaxf(u_s[i], 1e-8f);
                __syncthreads();
            }
            {
                float su = 0.f;
                for (int i = t; i < NROW; i += 1024) su += u_s[i];
                for (int o = 32; o; o >>= 1) su += __shfl_down(su, o, 64);
                if (lane == 0) v_s[wid] = su;
                __syncthreads();
                if (t < 64) {
                    float s2 = (t < 16) ? v_s[t] : 0.f;
                    for (int o = 8; o; o >>= 1) s2 += __shfl_down(s2, o, 64);
                    if (t == 0) v_s[0] = s2;
                }
                __syncthreads();
                float sum_u = v_s[0];
                __syncthreads();
                for (int i = t; i < NROW; i += 1024) v_s[i] = 1e-8f * sum_u;
                __syncthreads();
                for (int e = t; e < cnt; e += 1024)
                    atomicAdd(&v_s[list[e].j], list[e].s * u_s[list[e].i]);
                __syncthreads();
                for (int i = t; i < NROW; i += 1024) v_s[i] = AC / fmaxf(v_s[i], 1e-8f);
                __syncthreads();
            }
        }
        for (int i = t; i < NROW; i += 1024) { up[i] = u_s[i]; vp[i] = v_s[i]; }
        for (int e = t; e < cnt; e += 1024)
            sp += (double)u_s[list[e].i] * (double)v_s[list[e].j] * (double)list[e].t;
    }
    for (int o = 32; o; o >>= 1) sp += __shfl_down(sp, o, 64);
    if (lane == 0) atomicAdd(&acc[4], sp);
}

// wide-grid epilogue: Su, Sv, Sux2, Svy2, P[d], Q[d]
__global__ __launch_bounds__(256) void epi_k(const float* __restrict__ X,
                                             const float* __restrict__ Y,
                                             const float* __restrict__ x2,
                                             const float* __restrict__ y2,
                                             const float* __restrict__ u_g,
                                             const float* __restrict__ v_g,
                                             double* accum) {
    int p = blockIdx.y;
    const float* A = (p == 2) ? Y : X;
    const float* B = (p == 0) ? Y : ((p == 1) ? X : Y);
    const float* na = (p == 2) ? y2 : x2;
    const float* nb = (p == 0) ? y2 : ((p == 1) ? x2 : y2);
    const float* up = u_g + (size_t)p * NROW;
    const float* vp = v_g + (size_t)p * NROW;
    double* acc = accum + (size_t)p * 264;
    int t = threadIdx.x, lane = t & 63;
    int rbase = blockIdx.x * 256;
    {
        int r = rbase + t;
        double ui = up[r], vi = vp[r];
        double a0 = ui, a1 = vi, a2 = ui * (double)na[r], a3 = vi * (double)nb[r];
        for (int o = 32; o; o >>= 1) {
            a0 += __shfl_down(a0, o, 64); a1 += __shfl_down(a1, o, 64);
            a2 += __shfl_down(a2, o, 64); a3 += __shfl_down(a3, o, 64);
        }
        if (lane == 0) {
            atomicAdd(&acc[0], a0); atomicAdd(&acc[1], a1);
            atomicAdd(&acc[2], a2); atomicAdd(&acc[3], a3);
        }
    }
    {
        int dq = (t & 31) * 4, g = t >> 5;
        double pp[4] = {0, 0, 0, 0}, qq[4] = {0, 0, 0, 0};
        for (int k = 0; k < 32; k++) {
            int r = rbase + g + 8 * k;
            float4 av = *(const float4*)(A + (size_t)r * DDIM + dq);
            float us = up[r];
            pp[0] += (double)us * av.x; pp[1] += (double)us * av.y;
            pp[2] += (double)us * av.z; pp[3] += (double)us * av.w;
            float4 bv = *(const float4*)(B + (size_t)r * DDIM + dq);
            float vs = vp[r];
            qq[0] += (double)vs * bv.x; qq[1] += (double)vs * bv.y;
            qq[2] += (double)vs * bv.z; qq[3] += (double)vs * bv.w;
        }
        #pragma unroll
        for (int m = 0; m < 4; m++) {
            atomicAdd(&acc[8 + dq + m], pp[m]);
            atomicAdd(&acc[136 + dq + m], qq[m]);
        }
    }
}

__global__ void combine_k(const double* __restrict__ accum, float* __restrict__ out) {
    int t = threadIdx.x;  // 64 threads
    __shared__ double costs[3];
    for (int p = 0; p < 3; p++) {
        const double* acc = accum + (size_t)p * 264;
        double part = acc[8 + t] * acc[136 + t] + acc[8 + 64 + t] * acc[136 + 64 + t];
        for (int o = 32; o; o >>= 1) part += __shfl_down(part, o, 64);
        if (t == 0) {
            double F = acc[2] * acc[1] + acc[0] * acc[3] - 2.0 * part;
            double c = 1e-8 * F + acc[4];
            costs[p] = (c > 0.0) ? c : 0.0;
        }
    }
    __syncthreads();
    if (t == 0) {
        double dv = costs[0] - 0.5 * (costs[1] + costs[2]);
        dv = fmin(fmax(dv, 0.0), 10000.0);
        out[0] = (float)dv;
    }
}

extern "C" void kernel_launch(void* const* d_in, const int* in_sizes, int n_in,
                              void* d_out, int out_size, void* d_ws, size_t ws_size,
                              hipStream_t stream) {
    const float* X = (const float*)d_in[0];
    const float* Y = (const float*)d_in[1];
    float* out = (float*)d_out;
    char* ws = (char*)d_ws;
    float* x2 = (float*)ws;
    float* y2 = (float*)(ws + 32768);
    int* counts = (int*)(ws + 65536);
    double* accum = (double*)(ws + 65600);
    Entry* lists = (Entry*)(ws + 71936);
    unsigned short* Xbf = (unsigned short*)(ws + 858368);     // overlay region
    float* sdiag = (float*)(ws + 858368);
    float* tdiag = (float*)(ws + 956672);
    float* u_g = (float*)(ws + 1054976);
    float* v_g = (float*)(ws + 1153280);
    unsigned short* Ybf = (unsigned short*)(ws + 2955520);

    init_k<<<(3 * NROW + 255) / 256, 256, 0, stream>>>(counts, accum, lists);
    norms_k<<<(2 * NROW) / 4, 256, 0, stream>>>(X, Y, x2, y2, Xbf, Ybf);
    scan_k<<<dim3(64, 64, 3), 256, 0, stream>>>(Xbf, Ybf, x2, y2, counts, lists);
    exact_k<<<dim3(2048, 3), 256, 0, stream>>>(X, Y, x2, y2, counts, lists);
    compact_k<<<dim3(CAP / 256, 3), 256, 0, stream>>>(counts, lists, sdiag, tdiag, counts + 3);
    sink2_k<<<3, 1024, 0, stream>>>(counts, lists, sdiag, tdiag, u_g, v_g, accum);
    epi_k<<<dim3(NROW / 256, 3), 256, 0, stream>>>(X, Y, x2, y2, u_g, v_g, accum);
    combine_k<<<1, 64, 0, stream>>>(accum, out);
}

// Round 6
// 255.870 us; speedup vs baseline: 12.5505x; 1.5642x over previous
//
#include <hip/hip_runtime.h>
#include <math.h>

#define NROW 8192
#define DDIM 128
#define CAP 16384
#define NITERS 100
#define NWARM 6
#define AC (1.0f / 8192.0f)
#define LSTRIDE 136   // LDS row stride in bf16 elems

struct Entry { int i, j; float s, t; };

// ws layout (bytes):
// 0       : x2  float[NROW]              (32768)
// 32768   : y2  float[NROW]              (32768)
// 65536   : counts int[8]                { [0..2]=list counts (pre-seeded 8192 diag), [3..5]=off-diag active }
// 65600   : accum double[3][264]         { [0..4]=Su,Sv,Sux2,Svy2,Ssp [5]=R [6]=bu_f [7]=bv_f [8..]=P,Q }
// 71936   : lists Entry[3][CAP]          (786432) -> ends 858368
// 858368  : Xbf ushort[NROW*DDIM]        (2 MiB)   [OVERLAY: sdiag/tdiag/u_g/v_g — written after scan_k]
// 2955520 : Ybf ushort[NROW*DDIM]        (2 MiB)

typedef __attribute__((ext_vector_type(8))) short frag_ab;   // 8 bf16
typedef __attribute__((ext_vector_type(4))) float frag_cd;   // 4 fp32

__device__ inline unsigned short f2bf(float f) {
    unsigned u = __float_as_uint(f);
    return (unsigned short)((u + 0x7FFFu + ((u >> 16) & 1u)) >> 16);  // RN-even
}

__global__ void init_k(int* counts, double* accum, Entry* lists) {
    int idx = blockIdx.x * 256 + threadIdx.x;
    if (idx < 3) counts[idx] = NROW;          // diagonal pre-seeded below
    else if (idx < 8) counts[idx] = 0;
    if (idx < 3 * 264) accum[idx] = 0.0;
    if (idx < 3 * NROW) {
        int p = idx >> 13, i = idx & (NROW - 1);
        Entry e; e.i = i; e.j = i; e.s = 0.f; e.t = 0.f;
        lists[(size_t)p * CAP + i] = e;
    }
}

// norms + fp32->bf16 conversion
__global__ void norms_k(const float* __restrict__ X, const float* __restrict__ Y,
                        float* __restrict__ x2, float* __restrict__ y2,
                        unsigned short* __restrict__ Xbf, unsigned short* __restrict__ Ybf) {
    int gw = (blockIdx.x * blockDim.x + threadIdx.x) >> 6;
    int lane = threadIdx.x & 63;
    if (gw >= 2 * NROW) return;
    const float* M = (gw < NROW) ? X : Y;
    float* out = (gw < NROW) ? x2 : y2;
    unsigned short* Mb = (gw < NROW) ? Xbf : Ybf;
    int r = (gw < NROW) ? gw : gw - NROW;
    float2 v = *(const float2*)(M + (size_t)r * DDIM + lane * 2);
    unsigned pk = (unsigned)f2bf(v.x) | ((unsigned)f2bf(v.y) << 16);
    *(unsigned*)(Mb + (size_t)r * DDIM + lane * 2) = pk;
    float s = v.x * v.x + v.y * v.y;
    for (int o = 32; o; o >>= 1) s += __shfl_down(s, o, 64);
    if (lane == 0) out[r] = s;
}

// MFMA scan: C~ = x2[i]+y2[j]-2*(Xbf[i].Ybf[j]); push off-diag candidates C~<2.
__global__ __launch_bounds__(256) void scan_k(const unsigned short* __restrict__ Xbf,
                                              const unsigned short* __restrict__ Ybf,
                                              const float* __restrict__ x2,
                                              const float* __restrict__ y2,
                                              int* counts, Entry* lists) {
    int p = blockIdx.z;
    if (p && blockIdx.y < blockIdx.x) return;   // symmetric pairs: upper triangle only
    const unsigned short* Ab = (p == 2) ? Ybf : Xbf;
    const unsigned short* Bb = (p == 0) ? Ybf : ((p == 1) ? Xbf : Ybf);
    const float* na = (p == 2) ? y2 : x2;
    const float* nb = (p == 0) ? y2 : ((p == 1) ? x2 : y2);
    int i0 = blockIdx.x * 128, j0 = blockIdx.y * 128;

    __shared__ unsigned short As[128 * LSTRIDE];
    __shared__ unsigned short Bs[128 * LSTRIDE];
    int t = threadIdx.x;

    const unsigned short* ga = Ab + (size_t)i0 * DDIM;
    const unsigned short* gb = Bb + (size_t)j0 * DDIM;
    #pragma unroll
    for (int c = 0; c < 8; c++) {
        int u = c * 256 + t;
        int row = u >> 4, col = (u & 15) * 8;
        uint4 wa = *(const uint4*)(ga + u * 8);
        uint4 wb = *(const uint4*)(gb + u * 8);
        *(uint4*)&As[row * LSTRIDE + col] = wa;
        *(uint4*)&Bs[row * LSTRIDE + col] = wb;
    }
    __syncthreads();

    int w = t >> 6, lane = t & 63;
    int lm = lane & 15, quad = lane >> 4;
    int wr = (w & 1) * 64, wc = (w >> 1) * 64;

    frag_cd acc[4][4];
    #pragma unroll
    for (int rt = 0; rt < 4; rt++)
        #pragma unroll
        for (int ct = 0; ct < 4; ct++) acc[rt][ct] = (frag_cd){0.f, 0.f, 0.f, 0.f};

    int abase = (wr + lm) * LSTRIDE + quad * 8;
    int bbase = (wc + lm) * LSTRIDE + quad * 8;
    #pragma unroll
    for (int ks = 0; ks < 4; ks++) {
        int k0 = ks * 32;
        frag_ab a[4], b[4];
        #pragma unroll
        for (int rt = 0; rt < 4; rt++) a[rt] = *(const frag_ab*)&As[abase + rt * 16 * LSTRIDE + k0];
        #pragma unroll
        for (int ct = 0; ct < 4; ct++) b[ct] = *(const frag_ab*)&Bs[bbase + ct * 16 * LSTRIDE + k0];
        #pragma unroll
        for (int rt = 0; rt < 4; rt++)
            #pragma unroll
            for (int ct = 0; ct < 4; ct++)
                acc[rt][ct] = __builtin_amdgcn_mfma_f32_16x16x32_bf16(a[rt], b[ct], acc[rt][ct], 0, 0, 0);
    }

    Entry* list = lists + (size_t)p * CAP;
    #pragma unroll
    for (int rt = 0; rt < 4; rt++) {
        #pragma unroll
        for (int ct = 0; ct < 4; ct++) {
            int j = j0 + wc + ct * 16 + lm;
            float yj = nb[j];
            #pragma unroll
            for (int reg = 0; reg < 4; reg++) {
                int i = i0 + wr + rt * 16 + quad * 4 + reg;
                float Ct = na[i] + yj - 2.f * acc[rt][ct][reg];
                if (Ct < 2.0f && i != j) {
                    if (p == 0) {
                        int idx = atomicAdd(&counts[0], 1);
                        if (idx < CAP) { Entry e; e.i = i; e.j = j; e.s = 0.f; e.t = 0.f; list[idx] = e; }
                    } else if (i < j) {
                        int idx = atomicAdd(&counts[p], 2);
                        if (idx < CAP) { Entry e; e.i = i; e.j = j; e.s = 0.f; e.t = 0.f; list[idx] = e; }
                        if (idx + 1 < CAP) { Entry e; e.i = j; e.j = i; e.s = 0.f; e.t = 0.f; list[idx + 1] = e; }
                    }
                }
            }
        }
    }
}

// exact: full 128-dim fp32 distance for every listed entry.
__global__ __launch_bounds__(256) void exact_k(const float* __restrict__ X,
                                               const float* __restrict__ Y,
                                               const float* __restrict__ x2,
                                               const float* __restrict__ y2,
                                               const int* counts, Entry* lists) {
    int p = blockIdx.y;
    const float* A = (p == 2) ? Y : X;
    const float* B = (p == 0) ? Y : ((p == 1) ? X : Y);
    const float* na = (p == 2) ? y2 : x2;
    const float* nb = (p == 0) ? y2 : ((p == 1) ? x2 : y2);
    int cnt = counts[p]; if (cnt > CAP) cnt = CAP;
    Entry* list = lists + (size_t)p * CAP;
    int w = (blockIdx.x * 256 + threadIdx.x) >> 6;
    int lane = threadIdx.x & 63;
    for (int e = w; e < cnt; e += 8192) {
        int i = list[e].i, j = list[e].j;
        const float* ar = A + (size_t)i * DDIM;
        const float* br = B + (size_t)j * DDIM;
        float dot = ar[lane] * br[lane] + ar[lane + 64] * br[lane + 64];
        for (int o = 32; o; o >>= 1) dot += __shfl_down(dot, o, 64);
        if (lane == 0) {
            float raw = na[i] + nb[j] - 2.0f * dot;
            float C = fmaxf(raw, 0.0f);
            float sc = fmaxf(-C * 100.0f, -50.0f);
            float K = fmaxf(expf(sc), 1e-8f);
            float s = K - 1e-8f;
            list[e].s = s;
            list[e].t = (raw >= 0.f) ? s * C : (-1e-8f) * raw;   // exactly 0 when s==0
        }
    }
}

// compact: diagonal entries -> dense arrays; count active off-diagonal entries
__global__ void compact_k(const int* counts, const Entry* __restrict__ lists,
                          float* __restrict__ sdiag, float* __restrict__ tdiag,
                          int* rescnt) {
    int p = blockIdx.y;
    int cnt = counts[p]; if (cnt > CAP) cnt = CAP;
    int e = blockIdx.x * 256 + threadIdx.x;
    if (e >= cnt) return;
    Entry en = lists[(size_t)p * CAP + e];
    if (en.i == en.j) {
        sdiag[p * NROW + en.i] = en.s;
        tdiag[p * NROW + en.i] = en.t;
    } else if (en.s != 0.f || en.t != 0.f) {
        atomicAdd(&rescnt[p], 1);
    }
}

// Warm Sinkhorn: NWARM exact coupled iterations (cross-lane sums), then freeze
// bases bu,bv (sub-ulp drift beyond iter ~2) and hand off to sinkwide_k.
// Early bit-exact exit (period 1/2) still supported -> R=0.
__global__ __launch_bounds__(1024, 1) void sink2_k(const int* counts,
                                                   const Entry* __restrict__ lists,
                                                   const float* __restrict__ sdiag,
                                                   float* __restrict__ u_g,
                                                   float* __restrict__ v_g,
                                                   double* accum) {
    int p = blockIdx.x;
    const Entry* list = lists + (size_t)p * CAP;
    int cnt = counts[p]; if (cnt > CAP) cnt = CAP;
    int nres = counts[3 + p];
    double* acc = accum + (size_t)p * 264;
    float* up = u_g + (size_t)p * NROW;
    float* vp = v_g + (size_t)p * NROW;

    __shared__ float u_s[NROW];   // fallback only
    __shared__ float v_s[NROW];
    __shared__ float redS[2][16];
    __shared__ unsigned redC[16];
    int t = threadIdx.x;
    int wid = t >> 6, lane = t & 63;

    if (nres == 0) {
        float vk[8], uk[8], sk[8];
        unsigned pv2[8];
        #pragma unroll
        for (int k = 0; k < 8; k++) {
            sk[k] = sdiag[p * NROW + t + 1024 * k];
            vk[k] = 1.0f; uk[k] = AC; pv2[k] = 0xFFFFFFFFu;
        }
        unsigned flags = 3u;
        int par = 0, last = 0, done = 0;
        float bu_last = 0.f;
        for (int it = 0; it < NWARM; it++) {
            // phase A reduce: sum(v) + convergence flags
            float s = 0.f;
            #pragma unroll
            for (int k = 0; k < 8; k++) s += vk[k];
            for (int o = 32; o; o >>= 1) s += __shfl_down(s, o, 64);
            if (lane == 0) { redS[par][wid] = s; redC[wid] = flags; }
            __syncthreads();
            float sumv = 0.f; unsigned anyf = 0;
            #pragma unroll
            for (int w2 = 0; w2 < 16; w2++) { sumv += redS[par][w2]; anyf |= redC[w2]; }
            par ^= 1;
            if (it > 0) {
                if (!(anyf & 1)) { done = 1; break; }          // fixed point
                if (!(anyf & 2)) {                             // period-2 orbit
                    if (((NITERS - it) & 1) == 0) { done = 1; break; }
                    last = 1;
                }
            }
            float base = 1e-8f * sumv;
            #pragma unroll
            for (int k = 0; k < 8; k++) {
                float kv = fmaxf(base + sk[k] * vk[k], 1e-8f);
                uk[k] = AC * __builtin_amdgcn_rcpf(kv);
            }
            // phase B: sum(u), update v
            s = 0.f;
            #pragma unroll
            for (int k = 0; k < 8; k++) s += uk[k];
            for (int o = 32; o; o >>= 1) s += __shfl_down(s, o, 64);
            if (lane == 0) redS[par][wid] = s;
            __syncthreads();
            float sumu = 0.f;
            #pragma unroll
            for (int w2 = 0; w2 < 16; w2++) sumu += redS[par][w2];
            par ^= 1;
            base = 1e-8f * sumu;
            bu_last = base;
            unsigned d1 = 0, d2 = 0;
            #pragma unroll
            for (int k = 0; k < 8; k++) {
                float kv = fmaxf(base + sk[k] * uk[k], 1e-8f);
                float nv = AC * __builtin_amdgcn_rcpf(kv);
                unsigned nb_ = __float_as_uint(nv);
                d1 |= nb_ ^ __float_as_uint(vk[k]);
                d2 |= nb_ ^ pv2[k];
                pv2[k] = __float_as_uint(vk[k]);
                vk[k] = nv;
            }
            flags = (__any(d1 != 0) ? 1u : 0u) | (__any(d2 != 0) ? 2u : 0u);
            if (last) { done = 1; break; }
        }
        float bv_f = 0.f;
        int R = 0;
        if (!done) {
            // fresh sum(v) for the frozen bv
            float s = 0.f;
            #pragma unroll
            for (int k = 0; k < 8; k++) s += vk[k];
            for (int o = 32; o; o >>= 1) s += __shfl_down(s, o, 64);
            if (lane == 0) redS[par][wid] = s;
            __syncthreads();
            float sumv = 0.f;
            #pragma unroll
            for (int w2 = 0; w2 < 16; w2++) sumv += redS[par][w2];
            bv_f = 1e-8f * sumv;
            R = NITERS - NWARM;
        }
        #pragma unroll
        for (int k = 0; k < 8; k++) {
            int i = t + 1024 * k;
            up[i] = uk[k]; vp[i] = vk[k];
        }
        if (t == 0) { acc[5] = (double)R; acc[6] = (double)bu_last; acc[7] = (double)bv_f; }
    } else {
        // -------- fallback: general sparse scatter, full 100 iterations --------
        for (int i = t; i < NROW; i += 1024) { u_s[i] = 1.0f; v_s[i] = 1.0f; }
        __syncthreads();
        for (int it = 0; it < NITERS; it++) {
            {
                float sv = 0.f;
                for (int i = t; i < NROW; i += 1024) sv += v_s[i];
                for (int o = 32; o; o >>= 1) sv += __shfl_down(sv, o, 64);
                if (lane == 0) u_s[wid] = sv;
                __syncthreads();
                if (t < 64) {
                    float s2 = (t < 16) ? u_s[t] : 0.f;
                    for (int o = 8; o; o >>= 1) s2 += __shfl_down(s2, o, 64);
                    if (t == 0) u_s[0] = s2;
                }
                __syncthreads();
                float sum_v = u_s[0];
                __syncthreads();
                for (int i = t; i < NROW; i += 1024) u_s[i] = 1e-8f * sum_v;
                __syncthreads();
                for (int e = t; e < cnt; e += 1024)
                    atomicAdd(&u_s[list[e].i], list[e].s * v_s[list[e].j]);
                __syncthreads();
                for (int i = t; i < NROW; i += 1024) u_s[i] = AC / fmaxf(u_s[i], 1e-8f);
                __syncthreads();
            }
            {
                float su = 0.f;
                for (int i = t; i < NROW; i += 1024) su += u_s[i];
                for (int o = 32; o; o >>= 1) su += __shfl_down(su, o, 64);
                if (lane == 0) v_s[wid] = su;
                __syncthreads();
                if (t < 64) {
                    float s2 = (t < 16) ? v_s[t] : 0.f;
                    for (int o = 8; o; o >>= 1) s2 += __shfl_down(s2, o, 64);
                    if (t == 0) v_s[0] = s2;
                }
                __syncthreads();
                float sum_u = v_s[0];
                __syncthreads();
                for (int i = t; i < NROW; i += 1024) v_s[i] = 1e-8f * sum_u;
                __syncthreads();
                for (int e = t; e < cnt; e += 1024)
                    atomicAdd(&v_s[list[e].j], list[e].s * u_s[list[e].i]);
                __syncthreads();
                for (int i = t; i < NROW; i += 1024) v_s[i] = AC / fmaxf(v_s[i], 1e-8f);
                __syncthreads();
            }
        }
        for (int i = t; i < NROW; i += 1024) { up[i] = u_s[i]; vp[i] = v_s[i]; }
        if (t == 0) { acc[5] = 0.0; acc[6] = 0.0; acc[7] = 0.0; }
    }
}

// Frozen-base per-lane iterations: no barriers, no cross-lane traffic.
__global__ __launch_bounds__(256) void sinkwide_k(const float* __restrict__ sdiag,
                                                  float* __restrict__ u_g,
                                                  float* __restrict__ v_g,
                                                  const double* __restrict__ accum) {
    int p = blockIdx.y;
    const double* acc = accum + (size_t)p * 264;
    int R = (int)acc[5];
    if (R <= 0) return;
    float bu = (float)acc[6], bv = (float)acc[7];
    int i = blockIdx.x * 256 + threadIdx.x;
    float s = sdiag[p * NROW + i];
    float v = v_g[p * NROW + i];
    float u = u_g[p * NROW + i];
    for (int r = 0; r < R; r++) {
        u = AC * __builtin_amdgcn_rcpf(fmaxf(bv + s * v, 1e-8f));
        v = AC * __builtin_amdgcn_rcpf(fmaxf(bu + s * u, 1e-8f));
    }
    u_g[p * NROW + i] = u;
    v_g[p * NROW + i] = v;
}

// off-diagonal sparse cost correction (diagonal handled in epi_k via tdiag)
__global__ void sp_k(const int* counts, const Entry* __restrict__ lists,
                     const float* __restrict__ u_g, const float* __restrict__ v_g,
                     double* accum) {
    int p = blockIdx.x;
    int cnt = counts[p]; if (cnt > CAP) cnt = CAP;
    const Entry* list = lists + (size_t)p * CAP;
    const float* up = u_g + (size_t)p * NROW;
    const float* vp = v_g + (size_t)p * NROW;
    __shared__ double red[4];
    int t = threadIdx.x, lane = t & 63, wid = t >> 6;
    double sp = 0.0;
    for (int e = t; e < cnt; e += 256) {
        Entry en = list[e];
        if (en.i != en.j && en.t != 0.f)
            sp += (double)up[en.i] * (double)vp[en.j] * (double)en.t;
    }
    for (int o = 32; o; o >>= 1) sp += __shfl_down(sp, o, 64);
    if (lane == 0) red[wid] = sp;
    __syncthreads();
    if (t == 0) {
        double tot = red[0] + red[1] + red[2] + red[3];
        atomicAdd(&accum[(size_t)p * 264 + 4], tot);
    }
}

// wide-grid epilogue: Su, Sv, Sux2, Svy2, diag-sp, P[d], Q[d]
__global__ __launch_bounds__(256) void epi_k(const float* __restrict__ X,
                                             const float* __restrict__ Y,
                                             const float* __restrict__ x2,
                                             const float* __restrict__ y2,
                                             const float* __restrict__ u_g,
                                             const float* __restrict__ v_g,
                                             const float* __restrict__ tdiag,
                                             double* accum) {
    int p = blockIdx.y;
    const float* A = (p == 2) ? Y : X;
    const float* B = (p == 0) ? Y : ((p == 1) ? X : Y);
    const float* na = (p == 2) ? y2 : x2;
    const float* nb = (p == 0) ? y2 : ((p == 1) ? x2 : y2);
    const float* up = u_g + (size_t)p * NROW;
    const float* vp = v_g + (size_t)p * NROW;
    double* acc = accum + (size_t)p * 264;
    int t = threadIdx.x, lane = t & 63;
    int rbase = blockIdx.x * 256;
    {
        int r = rbase + t;
        double ui = up[r], vi = vp[r];
        double a0 = ui, a1 = vi, a2 = ui * (double)na[r], a3 = vi * (double)nb[r];
        double a4 = ui * vi * (double)tdiag[p * NROW + r];
        for (int o = 32; o; o >>= 1) {
            a0 += __shfl_down(a0, o, 64); a1 += __shfl_down(a1, o, 64);
            a2 += __shfl_down(a2, o, 64); a3 += __shfl_down(a3, o, 64);
            a4 += __shfl_down(a4, o, 64);
        }
        if (lane == 0) {
            atomicAdd(&acc[0], a0); atomicAdd(&acc[1], a1);
            atomicAdd(&acc[2], a2); atomicAdd(&acc[3], a3);
            atomicAdd(&acc[4], a4);
        }
    }
    {
        int dq = (t & 31) * 4, g = t >> 5;
        double pp[4] = {0, 0, 0, 0}, qq[4] = {0, 0, 0, 0};
        for (int k = 0; k < 32; k++) {
            int r = rbase + g + 8 * k;
            float4 av = *(const float4*)(A + (size_t)r * DDIM + dq);
            float us = up[r];
            pp[0] += (double)us * av.x; pp[1] += (double)us * av.y;
            pp[2] += (double)us * av.z; pp[3] += (double)us * av.w;
            float4 bv = *(const float4*)(B + (size_t)r * DDIM + dq);
            float vs = vp[r];
            qq[0] += (double)vs * bv.x; qq[1] += (double)vs * bv.y;
            qq[2] += (double)vs * bv.z; qq[3] += (double)vs * bv.w;
        }
        #pragma unroll
        for (int m = 0; m < 4; m++) {
            atomicAdd(&acc[8 + dq + m], pp[m]);
            atomicAdd(&acc[136 + dq + m], qq[m]);
        }
    }
}

__global__ void combine_k(const double* __restrict__ accum, float* __restrict__ out) {
    int t = threadIdx.x;  // 64 threads
    __shared__ double costs[3];
    for (int p = 0; p < 3; p++) {
        const double* acc = accum + (size_t)p * 264;
        double part = acc[8 + t] * acc[136 + t] + acc[8 + 64 + t] * acc[136 + 64 + t];
        for (int o = 32; o; o >>= 1) part += __shfl_down(part, o, 64);
        if (t == 0) {
            double F = acc[2] * acc[1] + acc[0] * acc[3] - 2.0 * part;
            double c = 1e-8 * F + acc[4];
            costs[p] = (c > 0.0) ? c : 0.0;
        }
    }
    __syncthreads();
    if (t == 0) {
        double dv = costs[0] - 0.5 * (costs[1] + costs[2]);
        dv = fmin(fmax(dv, 0.0), 10000.0);
        out[0] = (float)dv;
    }
}

extern "C" void kernel_launch(void* const* d_in, const int* in_sizes, int n_in,
                              void* d_out, int out_size, void* d_ws, size_t ws_size,
                              hipStream_t stream) {
    const float* X = (const float*)d_in[0];
    const float* Y = (const float*)d_in[1];
    float* out = (float*)d_out;
    char* ws = (char*)d_ws;
    float* x2 = (float*)ws;
    float* y2 = (float*)(ws + 32768);
    int* counts = (int*)(ws + 65536);
    double* accum = (double*)(ws + 65600);
    Entry* lists = (Entry*)(ws + 71936);
    unsigned short* Xbf = (unsigned short*)(ws + 858368);     // overlay region
    float* sdiag = (float*)(ws + 858368);
    float* tdiag = (float*)(ws + 956672);
    float* u_g = (float*)(ws + 1054976);
    float* v_g = (float*)(ws + 1153280);
    unsigned short* Ybf = (unsigned short*)(ws + 2955520);

    init_k<<<(3 * NROW + 255) / 256, 256, 0, stream>>>(counts, accum, lists);
    norms_k<<<(2 * NROW) / 4, 256, 0, stream>>>(X, Y, x2, y2, Xbf, Ybf);
    scan_k<<<dim3(64, 64, 3), 256, 0, stream>>>(Xbf, Ybf, x2, y2, counts, lists);
    exact_k<<<dim3(2048, 3), 256, 0, stream>>>(X, Y, x2, y2, counts, lists);
    compact_k<<<dim3(CAP / 256, 3), 256, 0, stream>>>(counts, lists, sdiag, tdiag, counts + 3);
    sink2_k<<<3, 1024, 0, stream>>>(counts, lists, sdiag, u_g, v_g, accum);
    sinkwide_k<<<dim3(NROW / 256, 3), 256, 0, stream>>>(sdiag, u_g, v_g, accum);
    sp_k<<<3, 256, 0, stream>>>(counts, lists, u_g, v_g, accum);
    epi_k<<<dim3(NROW / 256, 3), 256, 0, stream>>>(X, Y, x2, y2, u_g, v_g, tdiag, accum);
    combine_k<<<1, 64, 0, stream>>>(accum, out);
}